// Round 8
// baseline (385.675 us; speedup 1.0000x reference)
//
#include <hip/hip_runtime.h>
#include <math.h>

// ---------------------------------------------------------------------------
// TransNeXt aggregated attention. Round 8: attn_v6 — lane-quad per query
// (4 lanes x 8 channels), 8192 waves -> 32 waves/CU for latency hiding;
// pool bias precomputed (kills rpi->cpbT dependent gather in hot loop).
// B=4, H=W=64, C=256, NH=8, hd=32, LOCAL_LEN=9, pool 8x8=64
// ---------------------------------------------------------------------------

typedef unsigned short ushort_t;
typedef __attribute__((ext_vector_type(8))) short short8;
typedef __attribute__((ext_vector_type(4))) float f32x4;

static __device__ __forceinline__ unsigned short f2bf(float f) {
    unsigned int u = __float_as_uint(f);
    unsigned int lsb = (u >> 16) & 1u;
    u += 0x7fffu + lsb;                 // round-to-nearest-even
    return (unsigned short)(u >> 16);
}
static __device__ __forceinline__ float bf2f(unsigned short h) {
    return __uint_as_float(((unsigned int)h) << 16);
}

#define GLOAD16(g, l)                                                        \
    __builtin_amdgcn_global_load_lds(                                        \
        (const __attribute__((address_space(1))) unsigned int*)(g),          \
        (__attribute__((address_space(3))) unsigned int*)(l), 16, 0, 0)

// ---------------------------------------------------------------------------
// MFMA GEMM: C = A @ W^T + bias. 128x128 tile, BK=32. (unchanged)
// ---------------------------------------------------------------------------
template <bool SPLIT>
__global__ __launch_bounds__(256) void mfma_gemm(
    const ushort_t* __restrict__ Ahi_g, const ushort_t* __restrict__ Alo_g,
    const ushort_t* __restrict__ Bhi_g, const ushort_t* __restrict__ Blo_g,
    const float* __restrict__ bias, float* __restrict__ out0,
    float* __restrict__ out1, int mode)
{
    const int K = 256;
    __shared__ ushort_t Ah[128 * 32];
    __shared__ ushort_t Bh[128 * 32];
    __shared__ ushort_t Al[SPLIT ? 128 * 32 : 8];
    __shared__ ushort_t Bl[SPLIT ? 128 * 32 : 8];

    const int t = threadIdx.x;
    const int w = t >> 6;
    const int lane = t & 63;
    const int bm = blockIdx.y * 128;
    const int bn = blockIdx.x * 128;
    const int wm = (w >> 1) * 64;
    const int wn = (w & 1) * 64;

    f32x4 acc[4][4];
#pragma unroll
    for (int i = 0; i < 4; ++i)
#pragma unroll
        for (int j = 0; j < 4; ++j) acc[i][j] = f32x4{0.f, 0.f, 0.f, 0.f};

    const int lrow = lane >> 2;
    const int lk8  = (lane & 3) * 8;

    for (int k0 = 0; k0 < K; k0 += 32) {
#pragma unroll
        for (int r = 0; r < 2; ++r) {
            const int rowoff = r * 64 + w * 16;
            const int arow = bm + rowoff + lrow;
            const int brow = bn + rowoff + lrow;
            const unsigned ldsoff = (unsigned)rowoff * 32;
            GLOAD16(Ahi_g + (size_t)arow * K + k0 + lk8, &Ah[ldsoff]);
            GLOAD16(Bhi_g + (size_t)brow * K + k0 + lk8, &Bh[ldsoff]);
            if (SPLIT) {
                GLOAD16(Alo_g + (size_t)arow * K + k0 + lk8, &Al[ldsoff]);
                GLOAD16(Blo_g + (size_t)brow * K + k0 + lk8, &Bl[ldsoff]);
            }
        }
        __syncthreads();

        const int fr = lane & 15;
        const int fq = (lane >> 4) * 8;
        short8 ah[4], bh[4], al[4], bl[4];
#pragma unroll
        for (int i = 0; i < 4; ++i) {
            ah[i] = *(const short8*)&Ah[(wm + i * 16 + fr) * 32 + fq];
            if (SPLIT) al[i] = *(const short8*)&Al[(wm + i * 16 + fr) * 32 + fq];
        }
#pragma unroll
        for (int j = 0; j < 4; ++j) {
            bh[j] = *(const short8*)&Bh[(wn + j * 16 + fr) * 32 + fq];
            if (SPLIT) bl[j] = *(const short8*)&Bl[(wn + j * 16 + fr) * 32 + fq];
        }
#pragma unroll
        for (int i = 0; i < 4; ++i)
#pragma unroll
            for (int j = 0; j < 4; ++j) {
                acc[i][j] = __builtin_amdgcn_mfma_f32_16x16x32_bf16(ah[i], bh[j], acc[i][j], 0, 0, 0);
                if (SPLIT) {
                    acc[i][j] = __builtin_amdgcn_mfma_f32_16x16x32_bf16(ah[i], bl[j], acc[i][j], 0, 0, 0);
                    acc[i][j] = __builtin_amdgcn_mfma_f32_16x16x32_bf16(al[i], bh[j], acc[i][j], 0, 0, 0);
                }
            }
        __syncthreads();
    }

    const int fr = lane & 15;
    const int q4 = (lane >> 4) * 4;
#pragma unroll
    for (int i = 0; i < 4; ++i) {
#pragma unroll
        for (int j = 0; j < 4; ++j) {
            const int col = bn + wn + j * 16 + fr;
            const float bv = bias[col];
#pragma unroll
            for (int r = 0; r < 4; ++r) {
                const int row = bm + wm + i * 16 + q4 + r;
                float v = acc[i][j][r] + bv;
                if (mode == 0) {
                    if (col < 256) out0[(size_t)row * 256 + col] = v;
                    else           out1[(size_t)row * 512 + (col - 256)] = v;
                } else if (mode == 1) {
                    if (col < 256) out0[(size_t)row * 512 + 256 + col] = v;
                    else {
                        v = 0.5f * v * (1.0f + erff(v * 0.70710678118654752f));
                        out1[(size_t)row * 256 + (col - 256)] = v;
                    }
                } else {
                    out0[(size_t)row * 256 + col] = v;
                }
            }
        }
    }
}

// x (fp32) -> hi/lo bf16 pair
__global__ __launch_bounds__(256) void cast_split(
    const float4* __restrict__ x, ushort4* __restrict__ hi,
    ushort4* __restrict__ lo, int n4)
{
    int i = blockIdx.x * 256 + threadIdx.x;
    if (i >= n4) return;
    float4 v = x[i];
    ushort4 h, l;
    h.x = f2bf(v.x); l.x = f2bf(v.x - bf2f(h.x));
    h.y = f2bf(v.y); l.y = f2bf(v.y - bf2f(h.y));
    h.z = f2bf(v.z); l.z = f2bf(v.z - bf2f(h.z));
    h.w = f2bf(v.w); l.w = f2bf(v.w - bf2f(h.w));
    hi[i] = h; lo[i] = l;
}

// Build packed weight/bias buffers.
__global__ __launch_bounds__(256) void pack_weights(
    const float* __restrict__ qw, const float* __restrict__ kvw,
    const float* __restrict__ srw, const float* __restrict__ pw,
    const float* __restrict__ qb, const float* __restrict__ kvb,
    const float* __restrict__ srb,
    ushort_t* __restrict__ Wqkh, ushort_t* __restrict__ Wqkl,
    ushort_t* __restrict__ Wvs, ushort_t* __restrict__ Pw,
    float* __restrict__ bqk, float* __restrict__ bvs)
{
    int idx = blockIdx.x * 256 + threadIdx.x;
    if (idx < 131072) {
        int nn = idx >> 8, k = idx & 255;
        float a = (nn < 256) ? qw[nn * 256 + k] : kvw[(nn - 256) * 256 + k];
        unsigned short h = f2bf(a);
        Wqkh[idx] = h;
        Wqkl[idx] = f2bf(a - bf2f(h));
        float b = (nn < 256) ? kvw[(nn + 256) * 256 + k] : srw[(nn - 256) * 256 + k];
        Wvs[idx] = f2bf(b);
    }
    if (idx < 65536) Pw[idx] = f2bf(pw[idx]);
    if (idx < 512) bqk[idx] = (idx < 256) ? qb[idx] : kvb[idx - 256];
    else if (idx < 1024) {
        int r = idx - 512;
        bvs[r] = (r < 256) ? kvb[r + 256] : srb[r - 256];
    }
}

// pbias[(n*64+p)*8+h] = cpbT[rpi[n*64+p]*8+h]  (kills dependent gather)
__global__ __launch_bounds__(256) void bias_expand(
    const int* __restrict__ rpi, const float* __restrict__ cpbT,
    float* __restrict__ pbias)
{
    int idx = blockIdx.x * 256 + threadIdx.x;   // 0 .. 4096*64-1
    int r = rpi[idx];
    const float* c = cpbT + (size_t)r * 8;
    float4 a = *(const float4*)c;
    float4 b = *(const float4*)(c + 4);
    *(float4*)(pbias + (size_t)idx * 8 + 0) = a;
    *(float4*)(pbias + (size_t)idx * 8 + 4) = b;
}

// ------------------------- fp32 tile GEMM (kv_p only) -----------------------
#define BM 64
#define BN 64
#define BKK 16
__global__ __launch_bounds__(256) void gemm_bias_act(
    const float* __restrict__ A, const float* __restrict__ Wt,
    const float* __restrict__ bias, float* __restrict__ Cmat,
    int M, int N, int K, int act)
{
    __shared__ float As[BKK][BM + 4];
    __shared__ float Bs[BKK][BN + 4];
    const int tid = threadIdx.x;
    const int bm = blockIdx.y * BM;
    const int bn = blockIdx.x * BN;
    const int tr = (tid >> 4) << 2;
    const int tc = (tid & 15) << 2;
    const int lr = tid >> 2;
    const int lc = (tid & 3) << 2;
    float acc[4][4] = {{0.f}};

    for (int k0 = 0; k0 < K; k0 += BKK) {
        float4 av = *(const float4*)(A  + (size_t)(bm + lr) * K + k0 + lc);
        float4 wv = *(const float4*)(Wt + (size_t)(bn + lr) * K + k0 + lc);
        As[lc + 0][lr] = av.x; As[lc + 1][lr] = av.y;
        As[lc + 2][lr] = av.z; As[lc + 3][lr] = av.w;
        Bs[lc + 0][lr] = wv.x; Bs[lc + 1][lr] = wv.y;
        Bs[lc + 2][lr] = wv.z; Bs[lc + 3][lr] = wv.w;
        __syncthreads();
#pragma unroll
        for (int kk = 0; kk < BKK; ++kk) {
            float4 a  = *(const float4*)&As[kk][tr];
            float4 bq = *(const float4*)&Bs[kk][tc];
            float av4[4] = {a.x, a.y, a.z, a.w};
            float bv4[4] = {bq.x, bq.y, bq.z, bq.w};
#pragma unroll
            for (int ii = 0; ii < 4; ++ii)
#pragma unroll
                for (int jj = 0; jj < 4; ++jj)
                    acc[ii][jj] = fmaf(av4[ii], bv4[jj], acc[ii][jj]);
        }
        __syncthreads();
    }
#pragma unroll
    for (int ii = 0; ii < 4; ++ii) {
        int m = bm + tr + ii;
#pragma unroll
        for (int jj = 0; jj < 4; ++jj) {
            int nn = bn + tc + jj;
            float v = acc[ii][jj] + bias[nn];
            if (act == 1) v = 0.5f * v * (1.0f + erff(v * 0.70710678118654752f));
            Cmat[(size_t)m * N + nn] = v;
        }
    }
}

// L2-normalize first 256 channels of each row, per 32-channel head group
__global__ __launch_bounds__(256) void headnorm(float* __restrict__ buf, int rowStride)
{
    size_t row = blockIdx.x;
    int tid = threadIdx.x;
    float* p = buf + row * (size_t)rowStride + tid;
    float v = *p;
    float ss = v * v;
#pragma unroll
    for (int off = 16; off; off >>= 1) ss += __shfl_xor(ss, off, 32);
    *p = v / fmaxf(sqrtf(ss), 1e-12f);
}

// 8x8 average pool of x_sr (B,N,C) + LayerNorm -> xpool (B,64,C)
__global__ __launch_bounds__(256) void pool_ln(
    const float* __restrict__ xsr, const float* __restrict__ g,
    const float* __restrict__ be, float* __restrict__ xpool, int Hh, int Ww)
{
    const int C = 256;
    const int Nn = Hh * Ww;
    int b = blockIdx.x >> 6;
    int pidx = blockIdx.x & 63;
    int ph = pidx >> 3, pw = pidx & 7;
    int tid = threadIdx.x;
    float s = 0.f;
    for (int si = 0; si < 8; ++si) {
        int i = ph * 8 + si;
        const float* rowp = xsr + ((size_t)b * Nn + (size_t)i * Ww + pw * 8) * C + tid;
#pragma unroll
        for (int sj = 0; sj < 8; ++sj) s += rowp[(size_t)sj * C];
    }
    s *= (1.f / 64.f);
    __shared__ float red[256];
    red[tid] = s; __syncthreads();
    for (int st = 128; st; st >>= 1) { if (tid < st) red[tid] += red[tid + st]; __syncthreads(); }
    float mean = red[0] * (1.f / 256.f);
    __syncthreads();
    float dv = s - mean;
    red[tid] = dv * dv; __syncthreads();
    for (int st = 128; st; st >>= 1) { if (tid < st) red[tid] += red[tid + st]; __syncthreads(); }
    float var = red[0] * (1.f / 256.f);
    xpool[(size_t)blockIdx.x * C + tid] = dv * rsqrtf(var + 1e-5f) * g[tid] + be[tid];
}

// cpb = relu(table @ fc1^T + b1) @ fc2^T + b2
__global__ __launch_bounds__(256) void cpb_mlp(
    const float* __restrict__ table, const float* __restrict__ w1,
    const float* __restrict__ b1, const float* __restrict__ w2,
    const float* __restrict__ b2, float* __restrict__ outc)
{
    int row = blockIdx.x;
    float t0 = table[(size_t)row * 2], t1 = table[(size_t)row * 2 + 1];
    int tid = threadIdx.x;
    int tid2 = tid + 256;
    float h0 = fmaxf(fmaf(t1, w1[tid * 2 + 1],  fmaf(t0, w1[tid * 2],  b1[tid])),  0.f);
    float h1 = fmaxf(fmaf(t1, w1[tid2 * 2 + 1], fmaf(t0, w1[tid2 * 2], b1[tid2])), 0.f);
    __shared__ float red[256];
    for (int hh = 0; hh < 8; ++hh) {
        red[tid] = h0 * w2[hh * 512 + tid] + h1 * w2[hh * 512 + tid2];
        __syncthreads();
        for (int st = 128; st; st >>= 1) { if (tid < st) red[tid] += red[tid + st]; __syncthreads(); }
        if (tid == 0) outc[(size_t)row * 8 + hh] = red[0] + b2[hh];
        __syncthreads();
    }
}

// ---------------------------------------------------------------------------
// attn_v6: lane-quad per query (lanes 4k..4k+3; each lane owns 8 channels).
// Wave = 16 queries; block = 4 waves = 64 queries (one image row).
// 8192 waves total -> 32 waves/CU. Live set ~50 floats -> no spill.
// ---------------------------------------------------------------------------
__global__ __launch_bounds__(256) void attn_v6(
    const float* __restrict__ qraw, // (B,N,256) raw q (pre-norm)
    const float* __restrict__ kv,   // (B,N,512) k normed | v
    const float* __restrict__ kvp,  // (B,64,512) k_pool normed | v_pool
    const float* __restrict__ pbias,// (N,64,8) pool bias, pre-gathered
    const float* __restrict__ sls,  // (N)
    const float* __restrict__ temp, // (8)
    const float* __restrict__ qe,   // (8,32)
    const float* __restrict__ rbl,  // (8,9)
    const float* __restrict__ ltok, // (8,32,9)
    const float* __restrict__ lbias,// (8,9)
    ushort_t* __restrict__ attno_bf)// (B,N,256) bf16
{
    const int h = blockIdx.y, b = blockIdx.z;
    const int t = threadIdx.x;

    __shared__ float kp_s[64][32];   // broadcast reads -> no padding needed
    __shared__ float vp_s[64][32];
    __shared__ float lts[9][32];     // ltok[h] transposed: [l][d]
    __shared__ float rbl_s[9], lb_s[9], qe_s[32];

    {   // stage pool K/V: thread t -> token t>>2, channel 8-group (t&3)*8
        const int p = t >> 2;
        const int o8 = (t & 3) * 8;
        const float* g = kvp + ((size_t)(b * 64 + p)) * 512 + h * 32 + o8;
        *(float4*)&kp_s[p][o8 + 0] = *(const float4*)(g + 0);
        *(float4*)&kp_s[p][o8 + 4] = *(const float4*)(g + 4);
        *(float4*)&vp_s[p][o8 + 0] = *(const float4*)(g + 256);
        *(float4*)&vp_s[p][o8 + 4] = *(const float4*)(g + 260);
        for (int u = t; u < 288; u += 256) lts[u % 9][u / 9] = ltok[h * 288 + u];
        if (t < 9)  { rbl_s[t] = rbl[h * 9 + t]; lb_s[t] = lbias[h * 9 + t]; }
        if (t >= 64 && t < 96) qe_s[t - 64] = qe[h * 32 + (t - 64)];
    }
    __syncthreads();

    const int w = t >> 6;
    const int lane = t & 63;
    const int qi = lane >> 2;        // query within wave (0..15)
    const int co = (lane & 3) * 8;   // channel 8-group offset
    const int i = blockIdx.x;        // image row (one row per block)
    const int j = w * 16 + qi;       // query column
    const int n = i * 64 + j;
    const size_t gq = (size_t)b * 4096 + n;

    const float tm = temp[h];
    const float sp = (tm > 20.f) ? tm : log1pf(expf(tm));

    // ---- load q 8-slice, L2-normalize (quad-reduced sum of squares) ----
    float qv[8];
    {
        float ss = 0.f;
        const float4* qp = (const float4*)(qraw + gq * 256 + h * 32 + co);
#pragma unroll
        for (int c4 = 0; c4 < 2; ++c4) {
            float4 v = qp[c4];
            qv[4*c4+0] = v.x; qv[4*c4+1] = v.y; qv[4*c4+2] = v.z; qv[4*c4+3] = v.w;
            ss += v.x*v.x + v.y*v.y + v.z*v.z + v.w*v.w;
        }
        ss += __shfl_xor(ss, 1);
        ss += __shfl_xor(ss, 2);
        const float invn = 1.0f / fmaxf(sqrtf(ss), 1e-12f);
#pragma unroll
        for (int d = 0; d < 8; ++d) qv[d] *= invn;
    }

    // ---- learnable-token dots (q_norm; then qv becomes scaled q) ----
    float lt[9];
#pragma unroll
    for (int l = 0; l < 9; ++l) {
        float dl = 0.f;
        const float4* lw = (const float4*)&lts[l][co];
#pragma unroll
        for (int c4 = 0; c4 < 2; ++c4) {
            float4 w4 = lw[c4];
            dl += qv[4*c4+0]*w4.x + qv[4*c4+1]*w4.y + qv[4*c4+2]*w4.z + qv[4*c4+3]*w4.w;
        }
        dl += __shfl_xor(dl, 1);
        dl += __shfl_xor(dl, 2);
        lt[l] = dl + lb_s[l];
    }

    // ---- qv := scaled q slice ----
    const float scal = sp * sls[n];
#pragma unroll
    for (int d = 0; d < 8; ++d) qv[d] = (qv[d] + qe_s[co + d]) * scal;

    // ---- local scores (9 taps, raw; exp deferred) ----
    float sl[9];
#pragma unroll
    for (int l = 0; l < 9; ++l) {
        const int di = l / 3 - 1, dj = l % 3 - 1;
        const int ii = i + di;               // wave-uniform
        const int jn = j + dj;
        const bool ok = (ii >= 0) && (ii < 64) && (jn >= 0) && (jn < 64);
        const int ic = max(min(ii, 63), 0);
        const int jc = max(min(jn, 63), 0);
        const float4* kr = (const float4*)(kv + ((size_t)(b * 4096 + ic * 64 + jc)) * 512 + h * 32 + co);
        float dk = 0.f;
#pragma unroll
        for (int c4 = 0; c4 < 2; ++c4) {
            float4 k4 = kr[c4];
            dk += qv[4*c4+0]*k4.x + qv[4*c4+1]*k4.y + qv[4*c4+2]*k4.z + qv[4*c4+3]*k4.w;
        }
        dk += __shfl_xor(dk, 1);
        dk += __shfl_xor(dk, 2);
        sl[l] = ok ? (dk + rbl_s[l]) : -INFINITY;
    }

    // ---- running max from local scores (center tap always valid) ----
    float m = sl[0];
#pragma unroll
    for (int l = 1; l < 9; ++l) m = fmaxf(m, sl[l]);

    // ---- pool tokens: 8 chunks of 8, online softmax + AV ----
    float o[8];
#pragma unroll
    for (int d = 0; d < 8; ++d) o[d] = 0.f;
    float Z = 0.f;
    const float* pb = pbias + (size_t)n * 512 + h;   // stride 8 per token

    for (int cch = 0; cch < 8; ++cch) {
        float s8[8];
#pragma unroll
        for (int k = 0; k < 8; ++k) {
            const int p = cch * 8 + k;
            const float4* kr = (const float4*)&kp_s[p][co];
            float acc = 0.f;
#pragma unroll
            for (int c4 = 0; c4 < 2; ++c4) {
                float4 k4 = kr[c4];
                acc += qv[4*c4+0]*k4.x + qv[4*c4+1]*k4.y + qv[4*c4+2]*k4.z + qv[4*c4+3]*k4.w;
            }
            acc += __shfl_xor(acc, 1);
            acc += __shfl_xor(acc, 2);
            s8[k] = acc + pb[(size_t)p * 8];
        }
        float cmax = s8[0];
#pragma unroll
        for (int k = 1; k < 8; ++k) cmax = fmaxf(cmax, s8[k]);
        const float m_new = fmaxf(m, cmax);
        const float factor = __expf(m - m_new);   // ==1 when no new max
        Z *= factor;
#pragma unroll
        for (int d = 0; d < 8; ++d) o[d] *= factor;
        m = m_new;
#pragma unroll
        for (int k = 0; k < 8; ++k) {
            const float a = __expf(s8[k] - m);
            Z += a;
            const float4* vr = (const float4*)&vp_s[cch * 8 + k][co];
#pragma unroll
            for (int c4 = 0; c4 < 2; ++c4) {
                float4 v4 = vr[c4];
                o[4*c4+0] += a * v4.x; o[4*c4+1] += a * v4.y;
                o[4*c4+2] += a * v4.z; o[4*c4+3] += a * v4.w;
            }
        }
    }

    // ---- finish softmax: local exps with final m (overwrite sl) ----
#pragma unroll
    for (int l = 0; l < 9; ++l) { sl[l] = __expf(sl[l] - m); Z += sl[l]; }
    const float invZ = 1.0f / Z;
#pragma unroll
    for (int d = 0; d < 8; ++d) o[d] *= invZ;

    // ---- local AV (coef = a_local + lt; zero at OOB since v is zero-pad) ----
#pragma unroll
    for (int l = 0; l < 9; ++l) {
        const int di = l / 3 - 1, dj = l % 3 - 1;
        const int ii = i + di;
        const int jn = j + dj;
        const bool ok = (ii >= 0) && (ii < 64) && (jn >= 0) && (jn < 64);
        const int ic = max(min(ii, 63), 0);
        const int jc = max(min(jn, 63), 0);
        const float coef = ok ? (sl[l] * invZ + lt[l]) : 0.f;
        const float4* vr = (const float4*)(kv + ((size_t)(b * 4096 + ic * 64 + jc)) * 512 + 256 + h * 32 + co);
#pragma unroll
        for (int c4 = 0; c4 < 2; ++c4) {
            float4 v4 = vr[c4];
            o[4*c4+0] += coef * v4.x; o[4*c4+1] += coef * v4.y;
            o[4*c4+2] += coef * v4.z; o[4*c4+3] += coef * v4.w;
        }
    }

    // ---- store 8 bf16 (16 B per lane; quad covers 64 B contiguous) ----
    ushort4* outp = (ushort4*)(attno_bf + gq * 256 + h * 32 + co);
#pragma unroll
    for (int c4 = 0; c4 < 2; ++c4) {
        ushort4 u;
        u.x = f2bf(o[4*c4+0]); u.y = f2bf(o[4*c4+1]);
        u.z = f2bf(o[4*c4+2]); u.w = f2bf(o[4*c4+3]);
        outp[c4] = u;
    }
}

extern "C" void kernel_launch(void* const* d_in, const int* in_sizes, int n_in,
                              void* d_out, int out_size, void* d_ws, size_t ws_size,
                              hipStream_t stream)
{
    const float* x    = (const float*)d_in[0];
    const float* tbl  = (const float*)d_in[1];
    const float* sls  = (const float*)d_in[2];
    const float* q_w  = (const float*)d_in[3];
    const float* q_b  = (const float*)d_in[4];
    const float* kv_w = (const float*)d_in[5];
    const float* kv_b = (const float*)d_in[6];
    const float* temp = (const float*)d_in[7];
    const float* qe   = (const float*)d_in[8];
    const float* sr_w = (const float*)d_in[9];
    const float* sr_b = (const float*)d_in[10];
    const float* ng   = (const float*)d_in[11];
    const float* nb   = (const float*)d_in[12];
    const float* f1w  = (const float*)d_in[13];
    const float* f1b  = (const float*)d_in[14];
    const float* f2w  = (const float*)d_in[15];
    const float* f2b  = (const float*)d_in[16];
    const float* rbl  = (const float*)d_in[17];
    const float* ltok = (const float*)d_in[18];
    const float* lbias= (const float*)d_in[19];
    const float* pw   = (const float*)d_in[20];
    const float* pb   = (const float*)d_in[21];
    const int*   rpi  = (const int*)d_in[22];

    const int C = 256, Hh = 64, Ww = 64, Nn = Hh * Ww;
    const int B = in_sizes[0] / (Nn * C);   // 4
    const int T = in_sizes[1] / 2;
    const int M = B * Nn;                   // 16384

    float* ws = (float*)d_ws;
    size_t o = 0;
    float* qbuf  = ws + o; o += (size_t)M * C;
    float* kvbuf = ws + o; o += (size_t)M * 2 * C;
    float* xsr   = ws + o; o += (size_t)M * C;
    float* xpool = ws + o; o += (size_t)B * 64 * C;
    float* kvp   = ws + o; o += (size_t)B * 64 * 2 * C;
    float* cpbB  = ws + o; o += (size_t)T * 8;
    float* pbias = ws + o; o += (size_t)Nn * 64 * 8;               // 8 MB
    ushort_t* xhi = (ushort_t*)(ws + o); o += (size_t)M * C / 2;   // reused as attno_bf
    ushort_t* xlo = (ushort_t*)(ws + o); o += (size_t)M * C / 2;
    ushort_t* Wqkh = (ushort_t*)(ws + o); o += 512 * 256 / 2;
    ushort_t* Wqkl = (ushort_t*)(ws + o); o += 512 * 256 / 2;
    ushort_t* Wvs  = (ushort_t*)(ws + o); o += 512 * 256 / 2;
    ushort_t* Pwbf = (ushort_t*)(ws + o); o += 256 * 256 / 2;
    float* bqk = ws + o; o += 512;
    float* bvs = ws + o; o += 512;
    ushort_t* attno_bf = xhi;   // xhi dead after the two x-GEMMs

    dim3 blk(256);
    const int n4x = M * C / 4;

    // prepack
    cast_split<<<(n4x + 255) / 256, blk, 0, stream>>>((const float4*)x, (ushort4*)xhi, (ushort4*)xlo, n4x);
    pack_weights<<<512, blk, 0, stream>>>(q_w, kv_w, sr_w, pw, q_b, kv_b, sr_b,
                                          Wqkh, Wqkl, Wvs, Pwbf, bqk, bvs);
    // [q | k] split-precision GEMM; [v | sr] plain GEMM
    mfma_gemm<true ><<<dim3(4, M / 128), blk, 0, stream>>>(xhi, xlo, Wqkh, Wqkl, bqk, qbuf, kvbuf, 0);
    mfma_gemm<false><<<dim3(4, M / 128), blk, 0, stream>>>(xhi, xlo, Wvs,  Wvs,  bvs, kvbuf, xsr, 1);
    // normalize k (q is normalized in-lane inside attn_v6)
    headnorm<<<M, blk, 0, stream>>>(kvbuf, 2 * C);
    // pool + LN -> kv_p (fp32 GEMM, tiny) -> normalize k_pool
    pool_ln<<<B * 64, blk, 0, stream>>>(xsr, ng, nb, xpool, Hh, Ww);
    gemm_bias_act<<<dim3(2 * C / BN, (B * 64) / BM), blk, 0, stream>>>(xpool, kv_w, kv_b, kvp, B * 64, 2 * C, C, 0);
    headnorm<<<B * 64, blk, 0, stream>>>(kvp, 2 * C);
    // cpb + pool-bias expansion
    cpb_mlp<<<T, blk, 0, stream>>>(tbl, f1w, f1b, f2w, f2b, cpbB);
    bias_expand<<<(Nn * 64) / 256, blk, 0, stream>>>(rpi, cpbB, pbias);
    // attention (writes bf16 directly); grid: 64 rows x 8 heads x B
    attn_v6<<<dim3(64, 8, B), blk, 0, stream>>>(
        qbuf, kvbuf, kvp, pbias, sls, temp, qe, rbl, ltok, lbias, attno_bf);
    // proj (plain bf16 MFMA)
    mfma_gemm<false><<<dim3(2, M / 128), blk, 0, stream>>>(attno_bf, attno_bf, Pwbf, Pwbf, pb, (float*)d_out, (float*)d_out, 2);
}

// Round 9
// 303.708 us; speedup vs baseline: 1.2699x; 1.2699x over previous
//
#include <hip/hip_runtime.h>
#include <math.h>

// ---------------------------------------------------------------------------
// TransNeXt aggregated attention. Round 9: fp16 MFMA GEMMs, restructured for
// occupancy. Round 8 showed mfma_gemm at MfmaUtil 2.3% / 68 us: 512-block
// grids (2 blocks/CU) + 8 barrier-drained K-iters = latency-bound. Fix:
// 128x64 tiles (12 KB LDS, 4-5 blocks/CU resident), q|k|v|sr fused into one
// N=1024 GEMM (2048 blocks = 8/CU), fp16 single precision replaces
// split-bf16x3 (3x less MFMA work; fp16 logit error sigma ~0.013 vs bf16
// 0.075 -> no split needed).
// B=4, H=W=64, C=256, NH=8, hd=32, LOCAL_LEN=9, pool 8x8=64
// ---------------------------------------------------------------------------

typedef unsigned short ushort_t;
typedef __attribute__((ext_vector_type(8))) _Float16 half8;
typedef __attribute__((ext_vector_type(4))) float f32x4;

static __device__ __forceinline__ ushort_t f2h(float f) {
    _Float16 h = (_Float16)f;           // RTNE
    return *(ushort_t*)&h;
}

#define GLOAD16(g, l)                                                        \
    __builtin_amdgcn_global_load_lds(                                        \
        (const __attribute__((address_space(1))) unsigned int*)(g),          \
        (__attribute__((address_space(3))) unsigned int*)(l), 16, 0, 0)

// ---------------------------------------------------------------------------
// mfma_hgemm<TM>: C = A @ W^T + bias, fp16 inputs, fp32 out. Tile TM x 64,
// 256 threads = 2x2 waves, each wave (TM/2) x 32. BK=32, K=256.
// mode 0 (x-GEMM, N=1024): col<256 -> qbuf(256); <512 -> kvbuf k(512);
//   <768 -> kvbuf v(512,+256); else gelu -> xsr(256)
// mode 1 (proj, N=256): out0[row*256+col]
// ---------------------------------------------------------------------------
template <int TM>
__global__ __launch_bounds__(256) void mfma_hgemm(
    const ushort_t* __restrict__ Ag, const ushort_t* __restrict__ Bg,
    const float* __restrict__ bias, float* __restrict__ out0,
    float* __restrict__ out1, float* __restrict__ out2, int mode)
{
    const int K = 256;
    const int IM = TM / 32;              // row frags per wave (4 or 2)
    __shared__ ushort_t Ah[TM * 32];
    __shared__ ushort_t Bh[64 * 32];

    const int t = threadIdx.x;
    const int w = t >> 6;
    const int lane = t & 63;
    const int bm = blockIdx.y * TM;
    const int bn = blockIdx.x * 64;
    const int wr = w >> 1;               // wave row-half (0..1)
    const int wc = w & 1;                // wave col-half (0..1)
    const int wm = wr * (TM / 2);
    const int wn = wc * 32;

    f32x4 acc[IM][2];
#pragma unroll
    for (int i = 0; i < IM; ++i)
#pragma unroll
        for (int j = 0; j < 2; ++j) acc[i][j] = f32x4{0.f, 0.f, 0.f, 0.f};

    const int lrow = t >> 2;             // A/B staging row (thread-based)
    const int lk8  = (t & 3) * 8;

    for (int k0 = 0; k0 < K; k0 += 32) {
        // stage A (TM x 32) and B (64 x 32)
#pragma unroll
        for (int r = 0; r < TM / 64; ++r) {
            const int arow = r * 64 + lrow;          // lane-linear LDS order
            GLOAD16(Ag + (size_t)(bm + arow) * K + k0 + lk8,
                    &Ah[(unsigned)(r * 64 + (w * 16)) * 32]);
        }
        GLOAD16(Bg + (size_t)(bn + lrow) * K + k0 + lk8,
                &Bh[(unsigned)(w * 16) * 32]);
        __syncthreads();

        const int fr = lane & 15;
        const int fq = (lane >> 4) * 8;
        half8 af[IM], bf[2];
#pragma unroll
        for (int i = 0; i < IM; ++i)
            af[i] = *(const half8*)&Ah[(wm + i * 16 + fr) * 32 + fq];
#pragma unroll
        for (int j = 0; j < 2; ++j)
            bf[j] = *(const half8*)&Bh[(wn + j * 16 + fr) * 32 + fq];
#pragma unroll
        for (int i = 0; i < IM; ++i)
#pragma unroll
            for (int j = 0; j < 2; ++j)
                acc[i][j] = __builtin_amdgcn_mfma_f32_16x16x32_f16(af[i], bf[j], acc[i][j], 0, 0, 0);
        __syncthreads();
    }

    // epilogue: C/D layout col=lane&15, row=(lane>>4)*4+reg
    const int fr = lane & 15;
    const int q4 = (lane >> 4) * 4;
#pragma unroll
    for (int i = 0; i < IM; ++i) {
#pragma unroll
        for (int j = 0; j < 2; ++j) {
            const int col = bn + wn + j * 16 + fr;
            const float bv = bias[col];
#pragma unroll
            for (int r = 0; r < 4; ++r) {
                const int row = bm + wm + i * 16 + q4 + r;
                float v = acc[i][j][r] + bv;
                if (mode == 0) {
                    if (col < 256)      out0[(size_t)row * 256 + col] = v;
                    else if (col < 768) out1[(size_t)row * 512 + (col - 256)] = v;
                    else {
                        v = 0.5f * v * (1.0f + erff(v * 0.70710678118654752f));
                        out2[(size_t)row * 256 + (col - 768)] = v;
                    }
                } else {
                    out0[(size_t)row * 256 + col] = v;
                }
            }
        }
    }
}

// x (fp32) -> fp16
__global__ __launch_bounds__(256) void cast_half(
    const float4* __restrict__ x, ushort4* __restrict__ o, int n4)
{
    int i = blockIdx.x * 256 + threadIdx.x;
    if (i >= n4) return;
    float4 v = x[i];
    ushort4 h;
    h.x = f2h(v.x); h.y = f2h(v.y); h.z = f2h(v.z); h.w = f2h(v.w);
    o[i] = h;
}

// Pack Wall (1024x256 fp16): [q_w ; kv_w k-rows ; kv_w v-rows ; sr_w],
// ball (1024 fp32), Pw (256x256 fp16).
__global__ __launch_bounds__(256) void pack_weights2(
    const float* __restrict__ qw, const float* __restrict__ kvw,
    const float* __restrict__ srw, const float* __restrict__ pw,
    const float* __restrict__ qb, const float* __restrict__ kvb,
    const float* __restrict__ srb,
    ushort_t* __restrict__ Wall, ushort_t* __restrict__ Pw,
    float* __restrict__ ball)
{
    int idx = blockIdx.x * 256 + threadIdx.x;   // grid 1024 -> 262144
    if (idx < 262144) {
        int nn = idx >> 8, k = idx & 255;
        float a;
        if (nn < 256)      a = qw[nn * 256 + k];
        else if (nn < 768) a = kvw[(nn - 256) * 256 + k];   // k rows then v rows
        else               a = srw[(nn - 768) * 256 + k];
        Wall[idx] = f2h(a);
    }
    if (idx < 65536) Pw[idx] = f2h(pw[idx]);
    if (idx < 1024) {
        float bv;
        if (idx < 256)      bv = qb[idx];
        else if (idx < 768) bv = kvb[idx - 256];
        else                bv = srb[idx - 768];
        ball[idx] = bv;
    }
}

// pbias[(n*64+p)*8+h] = cpbT[rpi[n*64+p]*8+h]
__global__ __launch_bounds__(256) void bias_expand(
    const int* __restrict__ rpi, const float* __restrict__ cpbT,
    float* __restrict__ pbias)
{
    int idx = blockIdx.x * 256 + threadIdx.x;
    int r = rpi[idx];
    const float* c = cpbT + (size_t)r * 8;
    float4 a = *(const float4*)c;
    float4 b = *(const float4*)(c + 4);
    *(float4*)(pbias + (size_t)idx * 8 + 0) = a;
    *(float4*)(pbias + (size_t)idx * 8 + 4) = b;
}

// ------------------------- fp32 tile GEMM (kv_p only) -----------------------
#define BM 64
#define BN 64
#define BKK 16
__global__ __launch_bounds__(256) void gemm_bias_act(
    const float* __restrict__ A, const float* __restrict__ Wt,
    const float* __restrict__ bias, float* __restrict__ Cmat,
    int M, int N, int K, int act)
{
    __shared__ float As[BKK][BM + 4];
    __shared__ float Bs[BKK][BN + 4];
    const int tid = threadIdx.x;
    const int bm = blockIdx.y * BM;
    const int bn = blockIdx.x * BN;
    const int tr = (tid >> 4) << 2;
    const int tc = (tid & 15) << 2;
    const int lr = tid >> 2;
    const int lc = (tid & 3) << 2;
    float acc[4][4] = {{0.f}};

    for (int k0 = 0; k0 < K; k0 += BKK) {
        float4 av = *(const float4*)(A  + (size_t)(bm + lr) * K + k0 + lc);
        float4 wv = *(const float4*)(Wt + (size_t)(bn + lr) * K + k0 + lc);
        As[lc + 0][lr] = av.x; As[lc + 1][lr] = av.y;
        As[lc + 2][lr] = av.z; As[lc + 3][lr] = av.w;
        Bs[lc + 0][lr] = wv.x; Bs[lc + 1][lr] = wv.y;
        Bs[lc + 2][lr] = wv.z; Bs[lc + 3][lr] = wv.w;
        __syncthreads();
#pragma unroll
        for (int kk = 0; kk < BKK; ++kk) {
            float4 a  = *(const float4*)&As[kk][tr];
            float4 bq = *(const float4*)&Bs[kk][tc];
            float av4[4] = {a.x, a.y, a.z, a.w};
            float bv4[4] = {bq.x, bq.y, bq.z, bq.w};
#pragma unroll
            for (int ii = 0; ii < 4; ++ii)
#pragma unroll
                for (int jj = 0; jj < 4; ++jj)
                    acc[ii][jj] = fmaf(av4[ii], bv4[jj], acc[ii][jj]);
        }
        __syncthreads();
    }
#pragma unroll
    for (int ii = 0; ii < 4; ++ii) {
        int m = bm + tr + ii;
#pragma unroll
        for (int jj = 0; jj < 4; ++jj) {
            int nn = bn + tc + jj;
            float v = acc[ii][jj] + bias[nn];
            if (act == 1) v = 0.5f * v * (1.0f + erff(v * 0.70710678118654752f));
            Cmat[(size_t)m * N + nn] = v;
        }
    }
}

// L2-normalize first 256 channels of each row, per 32-channel head group
__global__ __launch_bounds__(256) void headnorm(float* __restrict__ buf, int rowStride)
{
    size_t row = blockIdx.x;
    int tid = threadIdx.x;
    float* p = buf + row * (size_t)rowStride + tid;
    float v = *p;
    float ss = v * v;
#pragma unroll
    for (int off = 16; off; off >>= 1) ss += __shfl_xor(ss, off, 32);
    *p = v / fmaxf(sqrtf(ss), 1e-12f);
}

// 8x8 average pool of x_sr (B,N,C) + LayerNorm -> xpool (B,64,C)
__global__ __launch_bounds__(256) void pool_ln(
    const float* __restrict__ xsr, const float* __restrict__ g,
    const float* __restrict__ be, float* __restrict__ xpool, int Hh, int Ww)
{
    const int C = 256;
    const int Nn = Hh * Ww;
    int b = blockIdx.x >> 6;
    int pidx = blockIdx.x & 63;
    int ph = pidx >> 3, pw = pidx & 7;
    int tid = threadIdx.x;
    float s = 0.f;
    for (int si = 0; si < 8; ++si) {
        int i = ph * 8 + si;
        const float* rowp = xsr + ((size_t)b * Nn + (size_t)i * Ww + pw * 8) * C + tid;
#pragma unroll
        for (int sj = 0; sj < 8; ++sj) s += rowp[(size_t)sj * C];
    }
    s *= (1.f / 64.f);
    __shared__ float red[256];
    red[tid] = s; __syncthreads();
    for (int st = 128; st; st >>= 1) { if (tid < st) red[tid] += red[tid + st]; __syncthreads(); }
    float mean = red[0] * (1.f / 256.f);
    __syncthreads();
    float dv = s - mean;
    red[tid] = dv * dv; __syncthreads();
    for (int st = 128; st; st >>= 1) { if (tid < st) red[tid] += red[tid + st]; __syncthreads(); }
    float var = red[0] * (1.f / 256.f);
    xpool[(size_t)blockIdx.x * C + tid] = dv * rsqrtf(var + 1e-5f) * g[tid] + be[tid];
}

// cpb = relu(table @ fc1^T + b1) @ fc2^T + b2
__global__ __launch_bounds__(256) void cpb_mlp(
    const float* __restrict__ table, const float* __restrict__ w1,
    const float* __restrict__ b1, const float* __restrict__ w2,
    const float* __restrict__ b2, float* __restrict__ outc)
{
    int row = blockIdx.x;
    float t0 = table[(size_t)row * 2], t1 = table[(size_t)row * 2 + 1];
    int tid = threadIdx.x;
    int tid2 = tid + 256;
    float h0 = fmaxf(fmaf(t1, w1[tid * 2 + 1],  fmaf(t0, w1[tid * 2],  b1[tid])),  0.f);
    float h1 = fmaxf(fmaf(t1, w1[tid2 * 2 + 1], fmaf(t0, w1[tid2 * 2], b1[tid2])), 0.f);
    __shared__ float red[256];
    for (int hh = 0; hh < 8; ++hh) {
        red[tid] = h0 * w2[hh * 512 + tid] + h1 * w2[hh * 512 + tid2];
        __syncthreads();
        for (int st = 128; st; st >>= 1) { if (tid < st) red[tid] += red[tid + st]; __syncthreads(); }
        if (tid == 0) outc[(size_t)row * 8 + hh] = red[0] + b2[hh];
        __syncthreads();
    }
}

// ---------------------------------------------------------------------------
// attn_v6 (unchanged structure from round 8; output now fp16 for proj GEMM)
// ---------------------------------------------------------------------------
__global__ __launch_bounds__(256) void attn_v6(
    const float* __restrict__ qraw, const float* __restrict__ kv,
    const float* __restrict__ kvp, const float* __restrict__ pbias,
    const float* __restrict__ sls, const float* __restrict__ temp,
    const float* __restrict__ qe, const float* __restrict__ rbl,
    const float* __restrict__ ltok, const float* __restrict__ lbias,
    ushort_t* __restrict__ attno_hf)
{
    const int h = blockIdx.y, b = blockIdx.z;
    const int t = threadIdx.x;

    __shared__ float kp_s[64][32];
    __shared__ float vp_s[64][32];
    __shared__ float lts[9][32];
    __shared__ float rbl_s[9], lb_s[9], qe_s[32];

    {
        const int p = t >> 2;
        const int o8 = (t & 3) * 8;
        const float* g = kvp + ((size_t)(b * 64 + p)) * 512 + h * 32 + o8;
        *(float4*)&kp_s[p][o8 + 0] = *(const float4*)(g + 0);
        *(float4*)&kp_s[p][o8 + 4] = *(const float4*)(g + 4);
        *(float4*)&vp_s[p][o8 + 0] = *(const float4*)(g + 256);
        *(float4*)&vp_s[p][o8 + 4] = *(const float4*)(g + 260);
        for (int u = t; u < 288; u += 256) lts[u % 9][u / 9] = ltok[h * 288 + u];
        if (t < 9)  { rbl_s[t] = rbl[h * 9 + t]; lb_s[t] = lbias[h * 9 + t]; }
        if (t >= 64 && t < 96) qe_s[t - 64] = qe[h * 32 + (t - 64)];
    }
    __syncthreads();

    const int w = t >> 6;
    const int lane = t & 63;
    const int qi = lane >> 2;
    const int co = (lane & 3) * 8;
    const int i = blockIdx.x;
    const int j = w * 16 + qi;
    const int n = i * 64 + j;
    const size_t gq = (size_t)b * 4096 + n;

    const float tm = temp[h];
    const float sp = (tm > 20.f) ? tm : log1pf(expf(tm));

    float qv[8];
    {
        float ss = 0.f;
        const float4* qp = (const float4*)(qraw + gq * 256 + h * 32 + co);
#pragma unroll
        for (int c4 = 0; c4 < 2; ++c4) {
            float4 v = qp[c4];
            qv[4*c4+0] = v.x; qv[4*c4+1] = v.y; qv[4*c4+2] = v.z; qv[4*c4+3] = v.w;
            ss += v.x*v.x + v.y*v.y + v.z*v.z + v.w*v.w;
        }
        ss += __shfl_xor(ss, 1);
        ss += __shfl_xor(ss, 2);
        const float invn = 1.0f / fmaxf(sqrtf(ss), 1e-12f);
#pragma unroll
        for (int d = 0; d < 8; ++d) qv[d] *= invn;
    }

    float lt[9];
#pragma unroll
    for (int l = 0; l < 9; ++l) {
        float dl = 0.f;
        const float4* lw = (const float4*)&lts[l][co];
#pragma unroll
        for (int c4 = 0; c4 < 2; ++c4) {
            float4 w4 = lw[c4];
            dl += qv[4*c4+0]*w4.x + qv[4*c4+1]*w4.y + qv[4*c4+2]*w4.z + qv[4*c4+3]*w4.w;
        }
        dl += __shfl_xor(dl, 1);
        dl += __shfl_xor(dl, 2);
        lt[l] = dl + lb_s[l];
    }

    const float scal = sp * sls[n];
#pragma unroll
    for (int d = 0; d < 8; ++d) qv[d] = (qv[d] + qe_s[co + d]) * scal;

    float sl[9];
#pragma unroll
    for (int l = 0; l < 9; ++l) {
        const int di = l / 3 - 1, dj = l % 3 - 1;
        const int ii = i + di;
        const int jn = j + dj;
        const bool ok = (ii >= 0) && (ii < 64) && (jn >= 0) && (jn < 64);
        const int ic = max(min(ii, 63), 0);
        const int jc = max(min(jn, 63), 0);
        const float4* kr = (const float4*)(kv + ((size_t)(b * 4096 + ic * 64 + jc)) * 512 + h * 32 + co);
        float dk = 0.f;
#pragma unroll
        for (int c4 = 0; c4 < 2; ++c4) {
            float4 k4 = kr[c4];
            dk += qv[4*c4+0]*k4.x + qv[4*c4+1]*k4.y + qv[4*c4+2]*k4.z + qv[4*c4+3]*k4.w;
        }
        dk += __shfl_xor(dk, 1);
        dk += __shfl_xor(dk, 2);
        sl[l] = ok ? (dk + rbl_s[l]) : -INFINITY;
    }

    float m = sl[0];
#pragma unroll
    for (int l = 1; l < 9; ++l) m = fmaxf(m, sl[l]);

    float o[8];
#pragma unroll
    for (int d = 0; d < 8; ++d) o[d] = 0.f;
    float Z = 0.f;
    const float* pb = pbias + (size_t)n * 512 + h;

    for (int cch = 0; cch < 8; ++cch) {
        float s8[8];
#pragma unroll
        for (int k = 0; k < 8; ++k) {
            const int p = cch * 8 + k;
            const float4* kr = (const float4*)&kp_s[p][co];
            float acc = 0.f;
#pragma unroll
            for (int c4 = 0; c4 < 2; ++c4) {
                float4 k4 = kr[c4];
                acc += qv[4*c4+0]*k4.x + qv[4*c4+1]*k4.y + qv[4*c4+2]*k4.z + qv[4*c4+3]*k4.w;
            }
            acc += __shfl_xor(acc, 1);
            acc += __shfl_xor(acc, 2);
            s8[k] = acc + pb[(size_t)p * 8];
        }
        float cmax = s8[0];
#pragma unroll
        for (int k = 1; k < 8; ++k) cmax = fmaxf(cmax, s8[k]);
        const float m_new = fmaxf(m, cmax);
        const float factor = __expf(m - m_new);
        Z *= factor;
#pragma unroll
        for (int d = 0; d < 8; ++d) o[d] *= factor;
        m = m_new;
#pragma unroll
        for (int k = 0; k < 8; ++k) {
            const float a = __expf(s8[k] - m);
            Z += a;
            const float4* vr = (const float4*)&vp_s[cch * 8 + k][co];
#pragma unroll
            for (int c4 = 0; c4 < 2; ++c4) {
                float4 v4 = vr[c4];
                o[4*c4+0] += a * v4.x; o[4*c4+1] += a * v4.y;
                o[4*c4+2] += a * v4.z; o[4*c4+3] += a * v4.w;
            }
        }
    }

#pragma unroll
    for (int l = 0; l < 9; ++l) { sl[l] = __expf(sl[l] - m); Z += sl[l]; }
    const float invZ = 1.0f / Z;
#pragma unroll
    for (int d = 0; d < 8; ++d) o[d] *= invZ;

#pragma unroll
    for (int l = 0; l < 9; ++l) {
        const int di = l / 3 - 1, dj = l % 3 - 1;
        const int ii = i + di;
        const int jn = j + dj;
        const bool ok = (ii >= 0) && (ii < 64) && (jn >= 0) && (jn < 64);
        const int ic = max(min(ii, 63), 0);
        const int jc = max(min(jn, 63), 0);
        const float coef = ok ? (sl[l] * invZ + lt[l]) : 0.f;
        const float4* vr = (const float4*)(kv + ((size_t)(b * 4096 + ic * 64 + jc)) * 512 + 256 + h * 32 + co);
#pragma unroll
        for (int c4 = 0; c4 < 2; ++c4) {
            float4 v4 = vr[c4];
            o[4*c4+0] += coef * v4.x; o[4*c4+1] += coef * v4.y;
            o[4*c4+2] += coef * v4.z; o[4*c4+3] += coef * v4.w;
        }
    }

    ushort4* outp = (ushort4*)(attno_hf + gq * 256 + h * 32 + co);
#pragma unroll
    for (int c4 = 0; c4 < 2; ++c4) {
        ushort4 u;
        u.x = f2h(o[4*c4+0]); u.y = f2h(o[4*c4+1]);
        u.z = f2h(o[4*c4+2]); u.w = f2h(o[4*c4+3]);
        outp[c4] = u;
    }
}

extern "C" void kernel_launch(void* const* d_in, const int* in_sizes, int n_in,
                              void* d_out, int out_size, void* d_ws, size_t ws_size,
                              hipStream_t stream)
{
    const float* x    = (const float*)d_in[0];
    const float* tbl  = (const float*)d_in[1];
    const float* sls  = (const float*)d_in[2];
    const float* q_w  = (const float*)d_in[3];
    const float* q_b  = (const float*)d_in[4];
    const float* kv_w = (const float*)d_in[5];
    const float* kv_b = (const float*)d_in[6];
    const float* temp = (const float*)d_in[7];
    const float* qe   = (const float*)d_in[8];
    const float* sr_w = (const float*)d_in[9];
    const float* sr_b = (const float*)d_in[10];
    const float* ng   = (const float*)d_in[11];
    const float* nb   = (const float*)d_in[12];
    const float* f1w  = (const float*)d_in[13];
    const float* f1b  = (const float*)d_in[14];
    const float* f2w  = (const float*)d_in[15];
    const float* f2b  = (const float*)d_in[16];
    const float* rbl  = (const float*)d_in[17];
    const float* ltok = (const float*)d_in[18];
    const float* lbias= (const float*)d_in[19];
    const float* pw   = (const float*)d_in[20];
    const float* pb   = (const float*)d_in[21];
    const int*   rpi  = (const int*)d_in[22];

    const int C = 256, Hh = 64, Ww = 64, Nn = Hh * Ww;
    const int B = in_sizes[0] / (Nn * C);   // 4
    const int T = in_sizes[1] / 2;
    const int M = B * Nn;                   // 16384

    float* ws = (float*)d_ws;
    size_t o = 0;
    float* qbuf  = ws + o; o += (size_t)M * C;
    float* kvbuf = ws + o; o += (size_t)M * 2 * C;
    float* xsr   = ws + o; o += (size_t)M * C;
    float* xpool = ws + o; o += (size_t)B * 64 * C;
    float* kvp   = ws + o; o += (size_t)B * 64 * 2 * C;
    float* cpbB  = ws + o; o += (size_t)T * 8;
    float* pbias = ws + o; o += (size_t)Nn * 64 * 8;               // 8 MB
    ushort_t* xh   = (ushort_t*)(ws + o); o += (size_t)M * C / 2;  // fp16 x; reused as attno
    ushort_t* Wall = (ushort_t*)(ws + o); o += 1024 * 256 / 2;
    ushort_t* Pwh  = (ushort_t*)(ws + o); o += 256 * 256 / 2;
    float* ball = ws + o; o += 1024;
    ushort_t* attno_hf = xh;   // xh dead after the x-GEMM

    dim3 blk(256);
    const int n4x = M * C / 4;

    // prepack
    cast_half<<<(n4x + 255) / 256, blk, 0, stream>>>((const float4*)x, (ushort4*)xh, n4x);
    pack_weights2<<<1024, blk, 0, stream>>>(q_w, kv_w, sr_w, pw, q_b, kv_b, sr_b,
                                            Wall, Pwh, ball);
    // fused [q | k | v | sr] fp16 GEMM: grid (1024/64, M/128) = (16,128) = 2048 blocks
    mfma_hgemm<128><<<dim3(16, M / 128), blk, 0, stream>>>(
        xh, Wall, ball, qbuf, kvbuf, xsr, 0);
    // normalize k (q normalized in-lane inside attn_v6)
    headnorm<<<M, blk, 0, stream>>>(kvbuf, 2 * C);
    // pool + LN -> kv_p (fp32 GEMM, tiny) -> normalize k_pool
    pool_ln<<<B * 64, blk, 0, stream>>>(xsr, ng, nb, xpool, Hh, Ww);
    gemm_bias_act<<<dim3(2 * C / BN, (B * 64) / BM), blk, 0, stream>>>(xpool, kv_w, kv_b, kvp, B * 64, 2 * C, C, 0);
    headnorm<<<B * 64, blk, 0, stream>>>(kvp, 2 * C);
    // cpb + pool-bias expansion
    cpb_mlp<<<T, blk, 0, stream>>>(tbl, f1w, f1b, f2w, f2b, cpbB);
    bias_expand<<<(Nn * 64) / 256, blk, 0, stream>>>(rpi, cpbB, pbias);
    // attention (writes fp16 directly)
    attn_v6<<<dim3(64, 8, B), blk, 0, stream>>>(
        qbuf, kvbuf, kvp, pbias, sls, temp, qe, rbl, ltok, lbias, attno_hf);
    // proj fp16 GEMM: grid (256/64, M/64) = (4,256) = 1024 blocks
    mfma_hgemm<64><<<dim3(4, M / 64), blk, 0, stream>>>(
        attno_hf, Pwh, pb, (float*)d_out, nullptr, nullptr, 1);
}

// Round 10
// 239.172 us; speedup vs baseline: 1.6125x; 1.2698x over previous
//
#include <hip/hip_runtime.h>
#include <math.h>

// ---------------------------------------------------------------------------
// TransNeXt aggregated attention. Round 10:
//  - attn_v7: fp16 K/V (LDS+global) -> ds_read count halved (the 41us LDS
//    floor from round 9's counters), fdot2 scores, pk_fma_f16 AV accumulate.
//  - cpb_mlp_v2: wave-per-row, shfl-only (old: T~14.6k blocks x 64 barriers).
//  - pbias transposed to (h,n,p): vectorized bias loads in attention.
// B=4, H=W=64, C=256, NH=8, hd=32, LOCAL_LEN=9, pool 8x8=64
// ---------------------------------------------------------------------------

typedef unsigned short ushort_t;
typedef __attribute__((ext_vector_type(8))) _Float16 half8;
typedef __attribute__((ext_vector_type(2))) _Float16 half2_t;
typedef __attribute__((ext_vector_type(4))) float f32x4;

static __device__ __forceinline__ ushort_t f2h(float f) {
    _Float16 h = (_Float16)f;           // RTNE
    return *(ushort_t*)&h;
}

static __device__ __forceinline__ float fdot2f(half2_t a, half2_t b, float c) {
#if __has_builtin(__builtin_amdgcn_fdot2)
    return __builtin_amdgcn_fdot2(a, b, c, false);
#else
    return (float)a[0] * (float)b[0] + (float)a[1] * (float)b[1] + c;
#endif
}

#define GLOAD16(g, l)                                                        \
    __builtin_amdgcn_global_load_lds(                                        \
        (const __attribute__((address_space(1))) unsigned int*)(g),          \
        (__attribute__((address_space(3))) unsigned int*)(l), 16, 0, 0)

// ---------------------------------------------------------------------------
// mfma_hgemm<TM>: C = A @ W^T + bias, fp16 in, fp32 accum. Tile TM x 64.
// mode 0 (x-GEMM, N=1024): col<256 -> qbuf fp32; col<768 -> kvh fp16
//   (row*512 + col-256: k then v); col>=768 -> gelu -> xsr fp32
// mode 1 (proj, N=256): out0 fp32
// ---------------------------------------------------------------------------
template <int TM>
__global__ __launch_bounds__(256) void mfma_hgemm(
    const ushort_t* __restrict__ Ag, const ushort_t* __restrict__ Bg,
    const float* __restrict__ bias, float* __restrict__ out0,
    ushort_t* __restrict__ kvh, float* __restrict__ out2, int mode)
{
    const int K = 256;
    const int IM = TM / 32;
    __shared__ ushort_t Ah[TM * 32];
    __shared__ ushort_t Bh[64 * 32];

    const int t = threadIdx.x;
    const int w = t >> 6;
    const int lane = t & 63;
    const int bm = blockIdx.y * TM;
    const int bn = blockIdx.x * 64;
    const int wm = (w >> 1) * (TM / 2);
    const int wn = (w & 1) * 32;

    f32x4 acc[IM][2];
#pragma unroll
    for (int i = 0; i < IM; ++i)
#pragma unroll
        for (int j = 0; j < 2; ++j) acc[i][j] = f32x4{0.f, 0.f, 0.f, 0.f};

    const int lrow = t >> 2;
    const int lk8  = (t & 3) * 8;

    for (int k0 = 0; k0 < K; k0 += 32) {
#pragma unroll
        for (int r = 0; r < TM / 64; ++r) {
            GLOAD16(Ag + (size_t)(bm + r * 64 + lrow) * K + k0 + lk8,
                    &Ah[(unsigned)(r * 64 + (w * 16)) * 32]);
        }
        GLOAD16(Bg + (size_t)(bn + lrow) * K + k0 + lk8,
                &Bh[(unsigned)(w * 16) * 32]);
        __syncthreads();

        const int fr = lane & 15;
        const int fq = (lane >> 4) * 8;
        half8 af[IM], bf[2];
#pragma unroll
        for (int i = 0; i < IM; ++i)
            af[i] = *(const half8*)&Ah[(wm + i * 16 + fr) * 32 + fq];
#pragma unroll
        for (int j = 0; j < 2; ++j)
            bf[j] = *(const half8*)&Bh[(wn + j * 16 + fr) * 32 + fq];
#pragma unroll
        for (int i = 0; i < IM; ++i)
#pragma unroll
            for (int j = 0; j < 2; ++j)
                acc[i][j] = __builtin_amdgcn_mfma_f32_16x16x32_f16(af[i], bf[j], acc[i][j], 0, 0, 0);
        __syncthreads();
    }

    const int fr = lane & 15;
    const int q4 = (lane >> 4) * 4;
#pragma unroll
    for (int i = 0; i < IM; ++i) {
#pragma unroll
        for (int j = 0; j < 2; ++j) {
            const int col = bn + wn + j * 16 + fr;
            const float bv = bias[col];
#pragma unroll
            for (int r = 0; r < 4; ++r) {
                const int row = bm + wm + i * 16 + q4 + r;
                float v = acc[i][j][r] + bv;
                if (mode == 0) {
                    if (col < 256)      out0[(size_t)row * 256 + col] = v;
                    else if (col < 768) kvh[(size_t)row * 512 + (col - 256)] = f2h(v);
                    else {
                        v = 0.5f * v * (1.0f + erff(v * 0.70710678118654752f));
                        out2[(size_t)row * 256 + (col - 768)] = v;
                    }
                } else {
                    out0[(size_t)row * 256 + col] = v;
                }
            }
        }
    }
}

// x (fp32) -> fp16
__global__ __launch_bounds__(256) void cast_half(
    const float4* __restrict__ x, ushort4* __restrict__ o, int n4)
{
    int i = blockIdx.x * 256 + threadIdx.x;
    if (i >= n4) return;
    float4 v = x[i];
    ushort4 h;
    h.x = f2h(v.x); h.y = f2h(v.y); h.z = f2h(v.z); h.w = f2h(v.w);
    o[i] = h;
}

// Wall (1024x256 fp16): [q_w ; kv_w k ; kv_w v ; sr_w]; ball (1024); Pw fp16.
__global__ __launch_bounds__(256) void pack_weights2(
    const float* __restrict__ qw, const float* __restrict__ kvw,
    const float* __restrict__ srw, const float* __restrict__ pw,
    const float* __restrict__ qb, const float* __restrict__ kvb,
    const float* __restrict__ srb,
    ushort_t* __restrict__ Wall, ushort_t* __restrict__ Pw,
    float* __restrict__ ball)
{
    int idx = blockIdx.x * 256 + threadIdx.x;
    if (idx < 262144) {
        int nn = idx >> 8, k = idx & 255;
        float a;
        if (nn < 256)      a = qw[nn * 256 + k];
        else if (nn < 768) a = kvw[(nn - 256) * 256 + k];
        else               a = srw[(nn - 768) * 256 + k];
        Wall[idx] = f2h(a);
    }
    if (idx < 65536) Pw[idx] = f2h(pw[idx]);
    if (idx < 1024) {
        float bv;
        if (idx < 256)      bv = qb[idx];
        else if (idx < 768) bv = kvb[idx - 256];
        else                bv = srb[idx - 768];
        ball[idx] = bv;
    }
}

// pbias[h][np] = cpbT[rpi[np]*8+h]  (transposed layout, coalesced r/w)
__global__ __launch_bounds__(256) void bias_expand_t(
    const int* __restrict__ rpi, const float* __restrict__ cpbT,
    float* __restrict__ pbias)
{
    int idx = blockIdx.x * 256 + threadIdx.x;   // 0 .. 8*262144-1
    int h = idx >> 18;
    int np = idx & 262143;
    pbias[idx] = cpbT[(size_t)rpi[np] * 8 + h];
}

// ------------------------- fp32 tile GEMM (kv_p only) -----------------------
#define BM 64
#define BN 64
#define BKK 16
__global__ __launch_bounds__(256) void gemm_bias_act(
    const float* __restrict__ A, const float* __restrict__ Wt,
    const float* __restrict__ bias, float* __restrict__ Cmat,
    int M, int N, int K, int act)
{
    __shared__ float As[BKK][BM + 4];
    __shared__ float Bs[BKK][BN + 4];
    const int tid = threadIdx.x;
    const int bm = blockIdx.y * BM;
    const int bn = blockIdx.x * BN;
    const int tr = (tid >> 4) << 2;
    const int tc = (tid & 15) << 2;
    const int lr = tid >> 2;
    const int lc = (tid & 3) << 2;
    float acc[4][4] = {{0.f}};

    for (int k0 = 0; k0 < K; k0 += BKK) {
        float4 av = *(const float4*)(A  + (size_t)(bm + lr) * K + k0 + lc);
        float4 wv = *(const float4*)(Wt + (size_t)(bn + lr) * K + k0 + lc);
        As[lc + 0][lr] = av.x; As[lc + 1][lr] = av.y;
        As[lc + 2][lr] = av.z; As[lc + 3][lr] = av.w;
        Bs[lc + 0][lr] = wv.x; Bs[lc + 1][lr] = wv.y;
        Bs[lc + 2][lr] = wv.z; Bs[lc + 3][lr] = wv.w;
        __syncthreads();
#pragma unroll
        for (int kk = 0; kk < BKK; ++kk) {
            float4 a  = *(const float4*)&As[kk][tr];
            float4 bq = *(const float4*)&Bs[kk][tc];
            float av4[4] = {a.x, a.y, a.z, a.w};
            float bv4[4] = {bq.x, bq.y, bq.z, bq.w};
#pragma unroll
            for (int ii = 0; ii < 4; ++ii)
#pragma unroll
                for (int jj = 0; jj < 4; ++jj)
                    acc[ii][jj] = fmaf(av4[ii], bv4[jj], acc[ii][jj]);
        }
        __syncthreads();
    }
#pragma unroll
    for (int ii = 0; ii < 4; ++ii) {
        int m = bm + tr + ii;
#pragma unroll
        for (int jj = 0; jj < 4; ++jj) {
            int nn = bn + tc + jj;
            float v = acc[ii][jj] + bias[nn];
            if (act == 1) v = 0.5f * v * (1.0f + erff(v * 0.70710678118654752f));
            Cmat[(size_t)m * N + nn] = v;
        }
    }
}

// L2-normalize first 256 channels per 32-ch head group (fp32, kv_p)
__global__ __launch_bounds__(256) void headnorm(float* __restrict__ buf, int rowStride)
{
    size_t row = blockIdx.x;
    int tid = threadIdx.x;
    float* p = buf + row * (size_t)rowStride + tid;
    float v = *p;
    float ss = v * v;
#pragma unroll
    for (int off = 16; off; off >>= 1) ss += __shfl_xor(ss, off, 32);
    *p = v / fmaxf(sqrtf(ss), 1e-12f);
}

// Same for fp16 buffer (k half of kvh, stride 512)
__global__ __launch_bounds__(256) void headnorm_h(ushort_t* __restrict__ buf)
{
    size_t row = blockIdx.x;
    int tid = threadIdx.x;
    ushort_t* p = buf + row * 512 + tid;
    float v = (float)(*(const _Float16*)p);
    float ss = v * v;
#pragma unroll
    for (int off = 16; off; off >>= 1) ss += __shfl_xor(ss, off, 32);
    *p = f2h(v / fmaxf(sqrtf(ss), 1e-12f));
}

// 8x8 average pool of x_sr (B,N,C) + LayerNorm -> xpool (B,64,C)
__global__ __launch_bounds__(256) void pool_ln(
    const float* __restrict__ xsr, const float* __restrict__ g,
    const float* __restrict__ be, float* __restrict__ xpool, int Hh, int Ww)
{
    const int C = 256;
    const int Nn = Hh * Ww;
    int b = blockIdx.x >> 6;
    int pidx = blockIdx.x & 63;
    int ph = pidx >> 3, pw = pidx & 7;
    int tid = threadIdx.x;
    float s = 0.f;
    for (int si = 0; si < 8; ++si) {
        int i = ph * 8 + si;
        const float* rowp = xsr + ((size_t)b * Nn + (size_t)i * Ww + pw * 8) * C + tid;
#pragma unroll
        for (int sj = 0; sj < 8; ++sj) s += rowp[(size_t)sj * C];
    }
    s *= (1.f / 64.f);
    __shared__ float red[256];
    red[tid] = s; __syncthreads();
    for (int st = 128; st; st >>= 1) { if (tid < st) red[tid] += red[tid + st]; __syncthreads(); }
    float mean = red[0] * (1.f / 256.f);
    __syncthreads();
    float dv = s - mean;
    red[tid] = dv * dv; __syncthreads();
    for (int st = 128; st; st >>= 1) { if (tid < st) red[tid] += red[tid + st]; __syncthreads(); }
    float var = red[0] * (1.f / 256.f);
    xpool[(size_t)blockIdx.x * C + tid] = dv * rsqrtf(var + 1e-5f) * g[tid] + be[tid];
}

// cpb MLP, wave-per-row, shfl-only (no barriers)
__global__ __launch_bounds__(256) void cpb_mlp_v2(
    const float* __restrict__ table, const float* __restrict__ w1,
    const float* __restrict__ b1, const float* __restrict__ w2,
    const float* __restrict__ b2, float* __restrict__ outc, int T)
{
    const int wv = threadIdx.x >> 6;
    const int lane = threadIdx.x & 63;
    const int row = blockIdx.x * 4 + wv;
    if (row >= T) return;
    const float t0 = table[(size_t)row * 2];
    const float t1 = table[(size_t)row * 2 + 1];
    const int base = lane * 8;

    const float4* w1p = (const float4*)(w1 + (size_t)base * 2);
    float4 wa = w1p[0], wb = w1p[1], wc = w1p[2], wd = w1p[3];
    float4 ba = *(const float4*)(b1 + base);
    float4 bb = *(const float4*)(b1 + base + 4);
    float h[8];
    h[0] = fmaxf(fmaf(t1, wa.y, fmaf(t0, wa.x, ba.x)), 0.f);
    h[1] = fmaxf(fmaf(t1, wa.w, fmaf(t0, wa.z, ba.y)), 0.f);
    h[2] = fmaxf(fmaf(t1, wb.y, fmaf(t0, wb.x, ba.z)), 0.f);
    h[3] = fmaxf(fmaf(t1, wb.w, fmaf(t0, wb.z, ba.w)), 0.f);
    h[4] = fmaxf(fmaf(t1, wc.y, fmaf(t0, wc.x, bb.x)), 0.f);
    h[5] = fmaxf(fmaf(t1, wc.w, fmaf(t0, wc.z, bb.y)), 0.f);
    h[6] = fmaxf(fmaf(t1, wd.y, fmaf(t0, wd.x, bb.z)), 0.f);
    h[7] = fmaxf(fmaf(t1, wd.w, fmaf(t0, wd.z, bb.w)), 0.f);

#pragma unroll
    for (int hh = 0; hh < 8; ++hh) {
        const float4* w2p = (const float4*)(w2 + (size_t)hh * 512 + base);
        float4 p0 = w2p[0], p1 = w2p[1];
        float s = h[0]*p0.x + h[1]*p0.y + h[2]*p0.z + h[3]*p0.w
                + h[4]*p1.x + h[5]*p1.y + h[6]*p1.z + h[7]*p1.w;
#pragma unroll
        for (int off = 1; off <= 32; off <<= 1) s += __shfl_xor(s, off);
        if (lane == 0) outc[(size_t)row * 8 + hh] = s + b2[hh];
    }
}

// ---------------------------------------------------------------------------
// attn_v7: lane-quad per query; fp16 K/V (1 ds_read_b128 per token per
// matrix), fdot2 scores, pk_fma_f16 AV accumulation (unnormalized; local
// coef = el + lt*Z; final *invZ).
// ---------------------------------------------------------------------------
__global__ __launch_bounds__(256) void attn_v7(
    const float* __restrict__ qraw,    // (B,N,256) fp32 raw q
    const ushort_t* __restrict__ kvh,  // (B,N,512) fp16: k normed | v
    const float* __restrict__ kvp,     // (B,64,512) fp32: k_pool normed | v_pool
    const float* __restrict__ pbias,   // (8,N,64) pool bias transposed
    const float* __restrict__ sls, const float* __restrict__ temp,
    const float* __restrict__ qe, const float* __restrict__ rbl,
    const float* __restrict__ ltok, const float* __restrict__ lbias,
    ushort_t* __restrict__ attno_hf)   // (B,N,256) fp16
{
    const int h = blockIdx.y, b = blockIdx.z;
    const int t = threadIdx.x;

    __shared__ half8 kp_s[64][4];    // 64 tokens x 32 ch fp16
    __shared__ half8 vp_s[64][4];
    __shared__ float lts[9][32];
    __shared__ float rbl_s[9], lb_s[9], qe_s[32];

    {   // stage pool K/V (fp32 -> fp16)
        const int p = t >> 2;
        const int g4 = t & 3;
        const float* g = kvp + ((size_t)(b * 64 + p)) * 512 + h * 32 + g4 * 8;
        float4 ka = *(const float4*)(g + 0);
        float4 kb = *(const float4*)(g + 4);
        float4 va = *(const float4*)(g + 256);
        float4 vb = *(const float4*)(g + 260);
        half8 kh, vh;
        kh[0]=(_Float16)ka.x; kh[1]=(_Float16)ka.y; kh[2]=(_Float16)ka.z; kh[3]=(_Float16)ka.w;
        kh[4]=(_Float16)kb.x; kh[5]=(_Float16)kb.y; kh[6]=(_Float16)kb.z; kh[7]=(_Float16)kb.w;
        vh[0]=(_Float16)va.x; vh[1]=(_Float16)va.y; vh[2]=(_Float16)va.z; vh[3]=(_Float16)va.w;
        vh[4]=(_Float16)vb.x; vh[5]=(_Float16)vb.y; vh[6]=(_Float16)vb.z; vh[7]=(_Float16)vb.w;
        kp_s[p][g4] = kh;
        vp_s[p][g4] = vh;
        for (int u = t; u < 288; u += 256) lts[u % 9][u / 9] = ltok[h * 288 + u];
        if (t < 9)  { rbl_s[t] = rbl[h * 9 + t]; lb_s[t] = lbias[h * 9 + t]; }
        if (t >= 64 && t < 96) qe_s[t - 64] = qe[h * 32 + (t - 64)];
    }
    __syncthreads();

    const int w = t >> 6;
    const int lane = t & 63;
    const int qi = lane >> 2;
    const int g4 = lane & 3;
    const int co = g4 * 8;
    const int i = blockIdx.x;
    const int j = w * 16 + qi;
    const int n = i * 64 + j;
    const size_t gq = (size_t)b * 4096 + n;

    const float tm = temp[h];
    const float sp = (tm > 20.f) ? tm : log1pf(expf(tm));

    // ---- load q slice, L2-normalize (quad reduce) ----
    float qv[8];
    {
        float ss = 0.f;
        const float4* qp = (const float4*)(qraw + gq * 256 + h * 32 + co);
#pragma unroll
        for (int c4 = 0; c4 < 2; ++c4) {
            float4 v = qp[c4];
            qv[4*c4+0] = v.x; qv[4*c4+1] = v.y; qv[4*c4+2] = v.z; qv[4*c4+3] = v.w;
            ss += v.x*v.x + v.y*v.y + v.z*v.z + v.w*v.w;
        }
        ss += __shfl_xor(ss, 1);
        ss += __shfl_xor(ss, 2);
        const float invn = 1.0f / fmaxf(sqrtf(ss), 1e-12f);
#pragma unroll
        for (int d = 0; d < 8; ++d) qv[d] *= invn;
    }

    // ---- learnable-token dots (fp32) ----
    float lt[9];
#pragma unroll
    for (int l = 0; l < 9; ++l) {
        float dl = 0.f;
        const float4* lw = (const float4*)&lts[l][co];
#pragma unroll
        for (int c4 = 0; c4 < 2; ++c4) {
            float4 w4 = lw[c4];
            dl += qv[4*c4+0]*w4.x + qv[4*c4+1]*w4.y + qv[4*c4+2]*w4.z + qv[4*c4+3]*w4.w;
        }
        dl += __shfl_xor(dl, 1);
        dl += __shfl_xor(dl, 2);
        lt[l] = dl + lb_s[l];
    }

    // ---- scaled q -> fp16 pairs ----
    const float scal = sp * sls[n];
    half2_t qh[4];
#pragma unroll
    for (int c = 0; c < 4; ++c) {
        float a = (qv[2*c+0] + qe_s[co + 2*c+0]) * scal;
        float bq = (qv[2*c+1] + qe_s[co + 2*c+1]) * scal;
        qh[c] = half2_t{(_Float16)a, (_Float16)bq};
    }

    // ---- local scores (fp16 k, fdot2) ----
    float sl[9];
#pragma unroll
    for (int l = 0; l < 9; ++l) {
        const int di = l / 3 - 1, dj = l % 3 - 1;
        const int ii = i + di;
        const int jn = j + dj;
        const bool ok = (ii >= 0) && (ii < 64) && (jn >= 0) && (jn < 64);
        const int ic = max(min(ii, 63), 0);
        const int jc = max(min(jn, 63), 0);
        const half8 k8 = *(const half8*)(kvh + ((size_t)(b * 4096 + ic * 64 + jc)) * 512 + h * 32 + co);
        float dk = 0.f;
        dk = fdot2f(qh[0], __builtin_shufflevector(k8, k8, 0, 1), dk);
        dk = fdot2f(qh[1], __builtin_shufflevector(k8, k8, 2, 3), dk);
        dk = fdot2f(qh[2], __builtin_shufflevector(k8, k8, 4, 5), dk);
        dk = fdot2f(qh[3], __builtin_shufflevector(k8, k8, 6, 7), dk);
        dk += __shfl_xor(dk, 1);
        dk += __shfl_xor(dk, 2);
        sl[l] = ok ? (dk + rbl_s[l]) : -INFINITY;
    }

    float m = sl[0];
#pragma unroll
    for (int l = 1; l < 9; ++l) m = fmaxf(m, sl[l]);

    // ---- pool: 8 chunks of 8, online softmax; AV in packed fp16 ----
    half2_t oh[4];
#pragma unroll
    for (int c = 0; c < 4; ++c) oh[c] = half2_t{(_Float16)0.f, (_Float16)0.f};
    float Z = 0.f;
    const float* plane = pbias + ((size_t)h << 18) + (size_t)n * 64;

    for (int cch = 0; cch < 8; ++cch) {
        float s8[8];
        float4 pb0 = *(const float4*)(plane + cch * 8);
        float4 pb1 = *(const float4*)(plane + cch * 8 + 4);
        const float pbv[8] = {pb0.x, pb0.y, pb0.z, pb0.w, pb1.x, pb1.y, pb1.z, pb1.w};
#pragma unroll
        for (int k = 0; k < 8; ++k) {
            const int p = cch * 8 + k;
            const half8 k8 = kp_s[p][g4];
            float acc = 0.f;
            acc = fdot2f(qh[0], __builtin_shufflevector(k8, k8, 0, 1), acc);
            acc = fdot2f(qh[1], __builtin_shufflevector(k8, k8, 2, 3), acc);
            acc = fdot2f(qh[2], __builtin_shufflevector(k8, k8, 4, 5), acc);
            acc = fdot2f(qh[3], __builtin_shufflevector(k8, k8, 6, 7), acc);
            acc += __shfl_xor(acc, 1);
            acc += __shfl_xor(acc, 2);
            s8[k] = acc + pbv[k];
        }
        float cmax = s8[0];
#pragma unroll
        for (int k = 1; k < 8; ++k) cmax = fmaxf(cmax, s8[k]);
        const float m_new = fmaxf(m, cmax);
        const float factor = __expf(m - m_new);
        Z *= factor;
        const _Float16 fh = (_Float16)factor;
        const half2_t f2 = half2_t{fh, fh};
#pragma unroll
        for (int c = 0; c < 4; ++c) oh[c] *= f2;
        m = m_new;
#pragma unroll
        for (int k = 0; k < 8; ++k) {
            const float a = __expf(s8[k] - m);
            Z += a;
            const _Float16 ah = (_Float16)a;
            const half2_t a2 = half2_t{ah, ah};
            const half8 v8 = vp_s[cch * 8 + k][g4];
            oh[0] = a2 * __builtin_shufflevector(v8, v8, 0, 1) + oh[0];
            oh[1] = a2 * __builtin_shufflevector(v8, v8, 2, 3) + oh[1];
            oh[2] = a2 * __builtin_shufflevector(v8, v8, 4, 5) + oh[2];
            oh[3] = a2 * __builtin_shufflevector(v8, v8, 6, 7) + oh[3];
        }
    }

    // ---- local exps with final m ----
#pragma unroll
    for (int l = 0; l < 9; ++l) { sl[l] = __expf(sl[l] - m); Z += sl[l]; }

    // ---- local AV: coef = el + lt*Z (unnormalized; final *invZ) ----
#pragma unroll
    for (int l = 0; l < 9; ++l) {
        const int di = l / 3 - 1, dj = l % 3 - 1;
        const int ii = i + di;
        const int jn = j + dj;
        const bool ok = (ii >= 0) && (ii < 64) && (jn >= 0) && (jn < 64);
        const int ic = max(min(ii, 63), 0);
        const int jc = max(min(jn, 63), 0);
        const float coef = ok ? (sl[l] + lt[l] * Z) : 0.f;
        const half8 v8 = *(const half8*)(kvh + ((size_t)(b * 4096 + ic * 64 + jc)) * 512 + 256 + h * 32 + co);
        const _Float16 ch = (_Float16)coef;
        const half2_t c2 = half2_t{ch, ch};
        oh[0] = c2 * __builtin_shufflevector(v8, v8, 0, 1) + oh[0];
        oh[1] = c2 * __builtin_shufflevector(v8, v8, 2, 3) + oh[1];
        oh[2] = c2 * __builtin_shufflevector(v8, v8, 4, 5) + oh[2];
        oh[3] = c2 * __builtin_shufflevector(v8, v8, 6, 7) + oh[3];
    }

    // ---- normalize and store fp16 ----
    const float invZ = 1.0f / Z;
    ushort4* outp = (ushort4*)(attno_hf + gq * 256 + h * 32 + co);
#pragma unroll
    for (int c4 = 0; c4 < 2; ++c4) {
        ushort4 u;
        u.x = f2h((float)oh[2*c4+0][0] * invZ);
        u.y = f2h((float)oh[2*c4+0][1] * invZ);
        u.z = f2h((float)oh[2*c4+1][0] * invZ);
        u.w = f2h((float)oh[2*c4+1][1] * invZ);
        outp[c4] = u;
    }
}

extern "C" void kernel_launch(void* const* d_in, const int* in_sizes, int n_in,
                              void* d_out, int out_size, void* d_ws, size_t ws_size,
                              hipStream_t stream)
{
    const float* x    = (const float*)d_in[0];
    const float* tbl  = (const float*)d_in[1];
    const float* sls  = (const float*)d_in[2];
    const float* q_w  = (const float*)d_in[3];
    const float* q_b  = (const float*)d_in[4];
    const float* kv_w = (const float*)d_in[5];
    const float* kv_b = (const float*)d_in[6];
    const float* temp = (const float*)d_in[7];
    const float* qe   = (const float*)d_in[8];
    const float* sr_w = (const float*)d_in[9];
    const float* sr_b = (const float*)d_in[10];
    const float* ng   = (const float*)d_in[11];
    const float* nb   = (const float*)d_in[12];
    const float* f1w  = (const float*)d_in[13];
    const float* f1b  = (const float*)d_in[14];
    const float* f2w  = (const float*)d_in[15];
    const float* f2b  = (const float*)d_in[16];
    const float* rbl  = (const float*)d_in[17];
    const float* ltok = (const float*)d_in[18];
    const float* lbias= (const float*)d_in[19];
    const float* pw   = (const float*)d_in[20];
    const float* pb   = (const float*)d_in[21];
    const int*   rpi  = (const int*)d_in[22];

    const int C = 256, Hh = 64, Ww = 64, Nn = Hh * Ww;
    const int B = in_sizes[0] / (Nn * C);   // 4
    const int T = in_sizes[1] / 2;
    const int M = B * Nn;                   // 16384

    float* ws = (float*)d_ws;
    size_t o = 0;
    float* qbuf  = ws + o; o += (size_t)M * C;                     // fp32
    ushort_t* kvh = (ushort_t*)(ws + o); o += (size_t)M * C;       // fp16 M x 512
    float* xsr   = ws + o; o += (size_t)M * C;
    float* xpool = ws + o; o += (size_t)B * 64 * C;
    float* kvp   = ws + o; o += (size_t)B * 64 * 2 * C;
    float* cpbB  = ws + o; o += (size_t)T * 8;
    float* pbias = ws + o; o += (size_t)8 * Nn * 64;               // 8 MB (h,n,p)
    ushort_t* xh   = (ushort_t*)(ws + o); o += (size_t)M * C / 2;  // fp16 x; reused as attno
    ushort_t* Wall = (ushort_t*)(ws + o); o += 1024 * 256 / 2;
    ushort_t* Pwh  = (ushort_t*)(ws + o); o += 256 * 256 / 2;
    float* ball = ws + o; o += 1024;
    ushort_t* attno_hf = xh;

    dim3 blk(256);
    const int n4x = M * C / 4;

    cast_half<<<(n4x + 255) / 256, blk, 0, stream>>>((const float4*)x, (ushort4*)xh, n4x);
    pack_weights2<<<1024, blk, 0, stream>>>(q_w, kv_w, sr_w, pw, q_b, kv_b, sr_b,
                                            Wall, Pwh, ball);
    // fused [q | k | v | sr]; k/v written fp16
    mfma_hgemm<128><<<dim3(16, M / 128), blk, 0, stream>>>(
        xh, Wall, ball, qbuf, kvh, xsr, 0);
    headnorm_h<<<M, blk, 0, stream>>>(kvh);
    pool_ln<<<B * 64, blk, 0, stream>>>(xsr, ng, nb, xpool, Hh, Ww);
    gemm_bias_act<<<dim3(2 * C / BN, (B * 64) / BM), blk, 0, stream>>>(xpool, kv_w, kv_b, kvp, B * 64, 2 * C, C, 0);
    headnorm<<<B * 64, blk, 0, stream>>>(kvp, 2 * C);
    cpb_mlp_v2<<<(T + 3) / 4, blk, 0, stream>>>(tbl, f1w, f1b, f2w, f2b, cpbB, T);
    bias_expand_t<<<(8 * Nn * 64) / 256, blk, 0, stream>>>(rpi, cpbB, pbias);
    attn_v7<<<dim3(64, 8, B), blk, 0, stream>>>(
        qbuf, kvh, kvp, pbias, sls, temp, qe, rbl, ltok, lbias, attno_hf);
    mfma_hgemm<64><<<dim3(4, M / 64), blk, 0, stream>>>(
        attno_hf, Pwh, pb, (float*)d_out, nullptr, nullptr, 1);
}

// Round 11
// 231.711 us; speedup vs baseline: 1.6645x; 1.0322x over previous
//
#include <hip/hip_runtime.h>
#include <math.h>

// ---------------------------------------------------------------------------
// TransNeXt aggregated attention. Round 11:
//  - k-head L2 norm fused into x-GEMM epilogue (in-register 16-lane shfl
//    reduction; wave-half == one head) -> headnorm_h kernel deleted.
//  - q and xsr stored fp16 (q renormalized in attn anyway) -> -32 MB traffic.
//  - cast_half + pack_weights2 merged into one prep kernel. 9 dispatches.
// B=4, H=W=64, C=256, NH=8, hd=32, LOCAL_LEN=9, pool 8x8=64
// ---------------------------------------------------------------------------

typedef unsigned short ushort_t;
typedef __attribute__((ext_vector_type(8))) _Float16 half8;
typedef __attribute__((ext_vector_type(2))) _Float16 half2_t;
typedef __attribute__((ext_vector_type(4))) float f32x4;

static __device__ __forceinline__ ushort_t f2h(float f) {
    _Float16 h = (_Float16)f;           // RTNE
    return *(ushort_t*)&h;
}

static __device__ __forceinline__ float fdot2f(half2_t a, half2_t b, float c) {
#if __has_builtin(__builtin_amdgcn_fdot2)
    return __builtin_amdgcn_fdot2(a, b, c, false);
#else
    return (float)a[0] * (float)b[0] + (float)a[1] * (float)b[1] + c;
#endif
}

#define GLOAD16(g, l)                                                        \
    __builtin_amdgcn_global_load_lds(                                        \
        (const __attribute__((address_space(1))) unsigned int*)(g),          \
        (__attribute__((address_space(3))) unsigned int*)(l), 16, 0, 0)

// ---------------------------------------------------------------------------
// mfma_hgemm<TM>: C = A @ W^T + bias, fp16 in, fp32 accum. Tile TM x 64.
// mode 0 (x-GEMM, N=1024): col<256 -> qh fp16; col<512 -> kvh k fp16 with
//   FUSED per-head L2 norm; col<768 -> kvh v fp16; else gelu -> xsrh fp16
// mode 1 (proj, N=256): out0 fp32
// ---------------------------------------------------------------------------
template <int TM>
__global__ __launch_bounds__(256) void mfma_hgemm(
    const ushort_t* __restrict__ Ag, const ushort_t* __restrict__ Bg,
    const float* __restrict__ bias, float* __restrict__ out0,
    ushort_t* __restrict__ qh_out, ushort_t* __restrict__ kvh,
    ushort_t* __restrict__ xsrh, int mode)
{
    const int K = 256;
    const int IM = TM / 32;
    __shared__ ushort_t Ah[TM * 32];
    __shared__ ushort_t Bh[64 * 32];

    const int t = threadIdx.x;
    const int w = t >> 6;
    const int lane = t & 63;
    const int bm = blockIdx.y * TM;
    const int bn = blockIdx.x * 64;
    const int wm = (w >> 1) * (TM / 2);
    const int wn = (w & 1) * 32;

    f32x4 acc[IM][2];
#pragma unroll
    for (int i = 0; i < IM; ++i)
#pragma unroll
        for (int j = 0; j < 2; ++j) acc[i][j] = f32x4{0.f, 0.f, 0.f, 0.f};

    const int lrow = t >> 2;
    const int lk8  = (t & 3) * 8;

    for (int k0 = 0; k0 < K; k0 += 32) {
#pragma unroll
        for (int r = 0; r < TM / 64; ++r) {
            GLOAD16(Ag + (size_t)(bm + r * 64 + lrow) * K + k0 + lk8,
                    &Ah[(unsigned)(r * 64 + (w * 16)) * 32]);
        }
        GLOAD16(Bg + (size_t)(bn + lrow) * K + k0 + lk8,
                &Bh[(unsigned)(w * 16) * 32]);
        __syncthreads();

        const int fr = lane & 15;
        const int fq = (lane >> 4) * 8;
        half8 af[IM], bf[2];
#pragma unroll
        for (int i = 0; i < IM; ++i)
            af[i] = *(const half8*)&Ah[(wm + i * 16 + fr) * 32 + fq];
#pragma unroll
        for (int j = 0; j < 2; ++j)
            bf[j] = *(const half8*)&Bh[(wn + j * 16 + fr) * 32 + fq];
#pragma unroll
        for (int i = 0; i < IM; ++i)
#pragma unroll
            for (int j = 0; j < 2; ++j)
                acc[i][j] = __builtin_amdgcn_mfma_f32_16x16x32_f16(af[i], bf[j], acc[i][j], 0, 0, 0);
        __syncthreads();
    }

    // epilogue: C/D layout col=lane&15, row=(lane>>4)*4+reg.
    // Within a 16-lane group the row is uniform; the wave-half's 32 cols are
    // 32-aligned -> exactly one head for the k range (fused L2 norm).
    const int fr = lane & 15;
    const int q4 = (lane >> 4) * 4;
#pragma unroll
    for (int i = 0; i < IM; ++i) {
#pragma unroll
        for (int r = 0; r < 4; ++r) {
            const int row = bm + wm + i * 16 + q4 + r;
            const int col0 = bn + wn + fr;
            const int col1 = col0 + 16;
            float v0 = acc[i][0][r] + bias[col0];
            float v1 = acc[i][1][r] + bias[col1];
            if (mode == 0) {
                if (col0 < 256) {
                    qh_out[(size_t)row * 256 + col0] = f2h(v0);
                    qh_out[(size_t)row * 256 + col1] = f2h(v1);
                } else if (col0 < 512) {       // k: fused per-head L2 norm
                    float ss = v0 * v0 + v1 * v1;
                    ss += __shfl_xor(ss, 1); ss += __shfl_xor(ss, 2);
                    ss += __shfl_xor(ss, 4); ss += __shfl_xor(ss, 8);
                    const float invn = 1.0f / fmaxf(sqrtf(ss), 1e-12f);
                    kvh[(size_t)row * 512 + (col0 - 256)] = f2h(v0 * invn);
                    kvh[(size_t)row * 512 + (col1 - 256)] = f2h(v1 * invn);
                } else if (col0 < 768) {       // v
                    kvh[(size_t)row * 512 + (col0 - 256)] = f2h(v0);
                    kvh[(size_t)row * 512 + (col1 - 256)] = f2h(v1);
                } else {                        // sr + gelu
                    v0 = 0.5f * v0 * (1.0f + erff(v0 * 0.70710678118654752f));
                    v1 = 0.5f * v1 * (1.0f + erff(v1 * 0.70710678118654752f));
                    xsrh[(size_t)row * 256 + (col0 - 768)] = f2h(v0);
                    xsrh[(size_t)row * 256 + (col1 - 768)] = f2h(v1);
                }
            } else {
                out0[(size_t)row * 256 + col0] = v0;
                out0[(size_t)row * 256 + col1] = v1;
            }
        }
    }
}

// prep: x fp32->fp16 cast + weight/bias packing in one kernel.
// Wall (1024x256 fp16): [q_w ; kv_w k ; kv_w v ; sr_w]; ball (1024); Pw fp16.
__global__ __launch_bounds__(256) void prep(
    const float4* __restrict__ x, ushort4* __restrict__ xh, int n4,
    const float* __restrict__ qw, const float* __restrict__ kvw,
    const float* __restrict__ srw, const float* __restrict__ pw,
    const float* __restrict__ qb, const float* __restrict__ kvb,
    const float* __restrict__ srb,
    ushort_t* __restrict__ Wall, ushort_t* __restrict__ Pw,
    float* __restrict__ ball)
{
    int idx = blockIdx.x * 256 + threadIdx.x;
    if (idx < n4) {
        float4 v = x[idx];
        ushort4 h;
        h.x = f2h(v.x); h.y = f2h(v.y); h.z = f2h(v.z); h.w = f2h(v.w);
        xh[idx] = h;
    }
    if (idx < 262144) {
        int nn = idx >> 8, k = idx & 255;
        float a;
        if (nn < 256)      a = qw[nn * 256 + k];
        else if (nn < 768) a = kvw[(nn - 256) * 256 + k];
        else               a = srw[(nn - 768) * 256 + k];
        Wall[idx] = f2h(a);
    }
    if (idx < 65536) Pw[idx] = f2h(pw[idx]);
    if (idx < 1024) {
        float bv;
        if (idx < 256)      bv = qb[idx];
        else if (idx < 768) bv = kvb[idx - 256];
        else                bv = srb[idx - 768];
        ball[idx] = bv;
    }
}

// pbias[h][np] = cpbT[rpi[np]*8+h]  (transposed, coalesced)
__global__ __launch_bounds__(256) void bias_expand_t(
    const int* __restrict__ rpi, const float* __restrict__ cpbT,
    float* __restrict__ pbias)
{
    int idx = blockIdx.x * 256 + threadIdx.x;
    int h = idx >> 18;
    int np = idx & 262143;
    pbias[idx] = cpbT[(size_t)rpi[np] * 8 + h];
}

// ------------------------- fp32 tile GEMM (kv_p only) -----------------------
#define BM 64
#define BN 64
#define BKK 16
__global__ __launch_bounds__(256) void gemm_bias_act(
    const float* __restrict__ A, const float* __restrict__ Wt,
    const float* __restrict__ bias, float* __restrict__ Cmat,
    int M, int N, int K, int act)
{
    __shared__ float As[BKK][BM + 4];
    __shared__ float Bs[BKK][BN + 4];
    const int tid = threadIdx.x;
    const int bm = blockIdx.y * BM;
    const int bn = blockIdx.x * BN;
    const int tr = (tid >> 4) << 2;
    const int tc = (tid & 15) << 2;
    const int lr = tid >> 2;
    const int lc = (tid & 3) << 2;
    float acc[4][4] = {{0.f}};

    for (int k0 = 0; k0 < K; k0 += BKK) {
        float4 av = *(const float4*)(A  + (size_t)(bm + lr) * K + k0 + lc);
        float4 wv = *(const float4*)(Wt + (size_t)(bn + lr) * K + k0 + lc);
        As[lc + 0][lr] = av.x; As[lc + 1][lr] = av.y;
        As[lc + 2][lr] = av.z; As[lc + 3][lr] = av.w;
        Bs[lc + 0][lr] = wv.x; Bs[lc + 1][lr] = wv.y;
        Bs[lc + 2][lr] = wv.z; Bs[lc + 3][lr] = wv.w;
        __syncthreads();
#pragma unroll
        for (int kk = 0; kk < BKK; ++kk) {
            float4 a  = *(const float4*)&As[kk][tr];
            float4 bq = *(const float4*)&Bs[kk][tc];
            float av4[4] = {a.x, a.y, a.z, a.w};
            float bv4[4] = {bq.x, bq.y, bq.z, bq.w};
#pragma unroll
            for (int ii = 0; ii < 4; ++ii)
#pragma unroll
                for (int jj = 0; jj < 4; ++jj)
                    acc[ii][jj] = fmaf(av4[ii], bv4[jj], acc[ii][jj]);
        }
        __syncthreads();
    }
#pragma unroll
    for (int ii = 0; ii < 4; ++ii) {
        int m = bm + tr + ii;
#pragma unroll
        for (int jj = 0; jj < 4; ++jj) {
            int nn = bn + tc + jj;
            float v = acc[ii][jj] + bias[nn];
            if (act == 1) v = 0.5f * v * (1.0f + erff(v * 0.70710678118654752f));
            Cmat[(size_t)m * N + nn] = v;
        }
    }
}

// L2-normalize first 256 channels per 32-ch head group (fp32, kv_p)
__global__ __launch_bounds__(256) void headnorm(float* __restrict__ buf, int rowStride)
{
    size_t row = blockIdx.x;
    int tid = threadIdx.x;
    float* p = buf + row * (size_t)rowStride + tid;
    float v = *p;
    float ss = v * v;
#pragma unroll
    for (int off = 16; off; off >>= 1) ss += __shfl_xor(ss, off, 32);
    *p = v / fmaxf(sqrtf(ss), 1e-12f);
}

// 8x8 average pool of x_sr fp16 (B,N,C) + LayerNorm -> xpool fp32 (B,64,C)
__global__ __launch_bounds__(256) void pool_ln(
    const ushort_t* __restrict__ xsr, const float* __restrict__ g,
    const float* __restrict__ be, float* __restrict__ xpool, int Hh, int Ww)
{
    const int C = 256;
    const int Nn = Hh * Ww;
    int b = blockIdx.x >> 6;
    int pidx = blockIdx.x & 63;
    int ph = pidx >> 3, pw = pidx & 7;
    int tid = threadIdx.x;
    float s = 0.f;
    for (int si = 0; si < 8; ++si) {
        int i = ph * 8 + si;
        const ushort_t* rowp = xsr + ((size_t)b * Nn + (size_t)i * Ww + pw * 8) * C + tid;
#pragma unroll
        for (int sj = 0; sj < 8; ++sj)
            s += (float)(*(const _Float16*)&rowp[(size_t)sj * C]);
    }
    s *= (1.f / 64.f);
    __shared__ float red[256];
    red[tid] = s; __syncthreads();
    for (int st = 128; st; st >>= 1) { if (tid < st) red[tid] += red[tid + st]; __syncthreads(); }
    float mean = red[0] * (1.f / 256.f);
    __syncthreads();
    float dv = s - mean;
    red[tid] = dv * dv; __syncthreads();
    for (int st = 128; st; st >>= 1) { if (tid < st) red[tid] += red[tid + st]; __syncthreads(); }
    float var = red[0] * (1.f / 256.f);
    xpool[(size_t)blockIdx.x * C + tid] = dv * rsqrtf(var + 1e-5f) * g[tid] + be[tid];
}

// cpb MLP, wave-per-row, shfl-only (no barriers)
__global__ __launch_bounds__(256) void cpb_mlp_v2(
    const float* __restrict__ table, const float* __restrict__ w1,
    const float* __restrict__ b1, const float* __restrict__ w2,
    const float* __restrict__ b2, float* __restrict__ outc, int T)
{
    const int wv = threadIdx.x >> 6;
    const int lane = threadIdx.x & 63;
    const int row = blockIdx.x * 4 + wv;
    if (row >= T) return;
    const float t0 = table[(size_t)row * 2];
    const float t1 = table[(size_t)row * 2 + 1];
    const int base = lane * 8;

    const float4* w1p = (const float4*)(w1 + (size_t)base * 2);
    float4 wa = w1p[0], wb = w1p[1], wc = w1p[2], wd = w1p[3];
    float4 ba = *(const float4*)(b1 + base);
    float4 bb = *(const float4*)(b1 + base + 4);
    float h[8];
    h[0] = fmaxf(fmaf(t1, wa.y, fmaf(t0, wa.x, ba.x)), 0.f);
    h[1] = fmaxf(fmaf(t1, wa.w, fmaf(t0, wa.z, ba.y)), 0.f);
    h[2] = fmaxf(fmaf(t1, wb.y, fmaf(t0, wb.x, ba.z)), 0.f);
    h[3] = fmaxf(fmaf(t1, wb.w, fmaf(t0, wb.z, ba.w)), 0.f);
    h[4] = fmaxf(fmaf(t1, wc.y, fmaf(t0, wc.x, bb.x)), 0.f);
    h[5] = fmaxf(fmaf(t1, wc.w, fmaf(t0, wc.z, bb.y)), 0.f);
    h[6] = fmaxf(fmaf(t1, wd.y, fmaf(t0, wd.x, bb.z)), 0.f);
    h[7] = fmaxf(fmaf(t1, wd.w, fmaf(t0, wd.z, bb.w)), 0.f);

#pragma unroll
    for (int hh = 0; hh < 8; ++hh) {
        const float4* w2p = (const float4*)(w2 + (size_t)hh * 512 + base);
        float4 p0 = w2p[0], p1 = w2p[1];
        float s = h[0]*p0.x + h[1]*p0.y + h[2]*p0.z + h[3]*p0.w
                + h[4]*p1.x + h[5]*p1.y + h[6]*p1.z + h[7]*p1.w;
#pragma unroll
        for (int off = 1; off <= 32; off <<= 1) s += __shfl_xor(s, off);
        if (lane == 0) outc[(size_t)row * 8 + hh] = s + b2[hh];
    }
}

// ---------------------------------------------------------------------------
// attn_v7: lane-quad per query; fp16 q/K/V; fdot2 scores; packed fp16 AV.
// ---------------------------------------------------------------------------
__global__ __launch_bounds__(256) void attn_v7(
    const ushort_t* __restrict__ qh_g, // (B,N,256) fp16 raw q
    const ushort_t* __restrict__ kvh,  // (B,N,512) fp16: k normed | v
    const float* __restrict__ kvp,     // (B,64,512) fp32: k_pool normed | v_pool
    const float* __restrict__ pbias,   // (8,N,64) pool bias transposed
    const float* __restrict__ sls, const float* __restrict__ temp,
    const float* __restrict__ qe, const float* __restrict__ rbl,
    const float* __restrict__ ltok, const float* __restrict__ lbias,
    ushort_t* __restrict__ attno_hf)   // (B,N,256) fp16
{
    const int h = blockIdx.y, b = blockIdx.z;
    const int t = threadIdx.x;

    __shared__ half8 kp_s[64][4];
    __shared__ half8 vp_s[64][4];
    __shared__ float lts[9][32];
    __shared__ float rbl_s[9], lb_s[9], qe_s[32];

    {
        const int p = t >> 2;
        const int g4 = t & 3;
        const float* g = kvp + ((size_t)(b * 64 + p)) * 512 + h * 32 + g4 * 8;
        float4 ka = *(const float4*)(g + 0);
        float4 kb = *(const float4*)(g + 4);
        float4 va = *(const float4*)(g + 256);
        float4 vb = *(const float4*)(g + 260);
        half8 kh, vh;
        kh[0]=(_Float16)ka.x; kh[1]=(_Float16)ka.y; kh[2]=(_Float16)ka.z; kh[3]=(_Float16)ka.w;
        kh[4]=(_Float16)kb.x; kh[5]=(_Float16)kb.y; kh[6]=(_Float16)kb.z; kh[7]=(_Float16)kb.w;
        vh[0]=(_Float16)va.x; vh[1]=(_Float16)va.y; vh[2]=(_Float16)va.z; vh[3]=(_Float16)va.w;
        vh[4]=(_Float16)vb.x; vh[5]=(_Float16)vb.y; vh[6]=(_Float16)vb.z; vh[7]=(_Float16)vb.w;
        kp_s[p][g4] = kh;
        vp_s[p][g4] = vh;
        for (int u = t; u < 288; u += 256) lts[u % 9][u / 9] = ltok[h * 288 + u];
        if (t < 9)  { rbl_s[t] = rbl[h * 9 + t]; lb_s[t] = lbias[h * 9 + t]; }
        if (t >= 64 && t < 96) qe_s[t - 64] = qe[h * 32 + (t - 64)];
    }
    __syncthreads();

    const int w = t >> 6;
    const int lane = t & 63;
    const int qi = lane >> 2;
    const int g4 = lane & 3;
    const int co = g4 * 8;
    const int i = blockIdx.x;
    const int j = w * 16 + qi;
    const int n = i * 64 + j;
    const size_t gq = (size_t)b * 4096 + n;

    const float tm = temp[h];
    const float sp = (tm > 20.f) ? tm : log1pf(expf(tm));

    // ---- load q slice (fp16), L2-normalize (quad reduce) ----
    float qv[8];
    {
        const half8 q8 = *(const half8*)(qh_g + gq * 256 + h * 32 + co);
        float ss = 0.f;
#pragma unroll
        for (int d = 0; d < 8; ++d) { qv[d] = (float)q8[d]; ss += qv[d] * qv[d]; }
        ss += __shfl_xor(ss, 1);
        ss += __shfl_xor(ss, 2);
        const float invn = 1.0f / fmaxf(sqrtf(ss), 1e-12f);
#pragma unroll
        for (int d = 0; d < 8; ++d) qv[d] *= invn;
    }

    // ---- learnable-token dots (fp32) ----
    float lt[9];
#pragma unroll
    for (int l = 0; l < 9; ++l) {
        float dl = 0.f;
        const float4* lw = (const float4*)&lts[l][co];
#pragma unroll
        for (int c4 = 0; c4 < 2; ++c4) {
            float4 w4 = lw[c4];
            dl += qv[4*c4+0]*w4.x + qv[4*c4+1]*w4.y + qv[4*c4+2]*w4.z + qv[4*c4+3]*w4.w;
        }
        dl += __shfl_xor(dl, 1);
        dl += __shfl_xor(dl, 2);
        lt[l] = dl + lb_s[l];
    }

    // ---- scaled q -> fp16 pairs ----
    const float scal = sp * sls[n];
    half2_t qh[4];
#pragma unroll
    for (int c = 0; c < 4; ++c) {
        float a = (qv[2*c+0] + qe_s[co + 2*c+0]) * scal;
        float bq = (qv[2*c+1] + qe_s[co + 2*c+1]) * scal;
        qh[c] = half2_t{(_Float16)a, (_Float16)bq};
    }

    // ---- local scores (fp16 k, fdot2) ----
    float sl[9];
#pragma unroll
    for (int l = 0; l < 9; ++l) {
        const int di = l / 3 - 1, dj = l % 3 - 1;
        const int ii = i + di;
        const int jn = j + dj;
        const bool ok = (ii >= 0) && (ii < 64) && (jn >= 0) && (jn < 64);
        const int ic = max(min(ii, 63), 0);
        const int jc = max(min(jn, 63), 0);
        const half8 k8 = *(const half8*)(kvh + ((size_t)(b * 4096 + ic * 64 + jc)) * 512 + h * 32 + co);
        float dk = 0.f;
        dk = fdot2f(qh[0], __builtin_shufflevector(k8, k8, 0, 1), dk);
        dk = fdot2f(qh[1], __builtin_shufflevector(k8, k8, 2, 3), dk);
        dk = fdot2f(qh[2], __builtin_shufflevector(k8, k8, 4, 5), dk);
        dk = fdot2f(qh[3], __builtin_shufflevector(k8, k8, 6, 7), dk);
        dk += __shfl_xor(dk, 1);
        dk += __shfl_xor(dk, 2);
        sl[l] = ok ? (dk + rbl_s[l]) : -INFINITY;
    }

    float m = sl[0];
#pragma unroll
    for (int l = 1; l < 9; ++l) m = fmaxf(m, sl[l]);

    // ---- pool: 8 chunks of 8, online softmax; AV in packed fp16 ----
    half2_t oh[4];
#pragma unroll
    for (int c = 0; c < 4; ++c) oh[c] = half2_t{(_Float16)0.f, (_Float16)0.f};
    float Z = 0.f;
    const float* plane = pbias + ((size_t)h << 18) + (size_t)n * 64;

    for (int cch = 0; cch < 8; ++cch) {
        float s8[8];
        float4 pb0 = *(const float4*)(plane + cch * 8);
        float4 pb1 = *(const float4*)(plane + cch * 8 + 4);
        const float pbv[8] = {pb0.x, pb0.y, pb0.z, pb0.w, pb1.x, pb1.y, pb1.z, pb1.w};
#pragma unroll
        for (int k = 0; k < 8; ++k) {
            const int p = cch * 8 + k;
            const half8 k8 = kp_s[p][g4];
            float acc = 0.f;
            acc = fdot2f(qh[0], __builtin_shufflevector(k8, k8, 0, 1), acc);
            acc = fdot2f(qh[1], __builtin_shufflevector(k8, k8, 2, 3), acc);
            acc = fdot2f(qh[2], __builtin_shufflevector(k8, k8, 4, 5), acc);
            acc = fdot2f(qh[3], __builtin_shufflevector(k8, k8, 6, 7), acc);
            acc += __shfl_xor(acc, 1);
            acc += __shfl_xor(acc, 2);
            s8[k] = acc + pbv[k];
        }
        float cmax = s8[0];
#pragma unroll
        for (int k = 1; k < 8; ++k) cmax = fmaxf(cmax, s8[k]);
        const float m_new = fmaxf(m, cmax);
        const float factor = __expf(m - m_new);
        Z *= factor;
        const _Float16 fh = (_Float16)factor;
        const half2_t f2 = half2_t{fh, fh};
#pragma unroll
        for (int c = 0; c < 4; ++c) oh[c] *= f2;
        m = m_new;
#pragma unroll
        for (int k = 0; k < 8; ++k) {
            const float a = __expf(s8[k] - m);
            Z += a;
            const _Float16 ah = (_Float16)a;
            const half2_t a2 = half2_t{ah, ah};
            const half8 v8 = vp_s[cch * 8 + k][g4];
            oh[0] = a2 * __builtin_shufflevector(v8, v8, 0, 1) + oh[0];
            oh[1] = a2 * __builtin_shufflevector(v8, v8, 2, 3) + oh[1];
            oh[2] = a2 * __builtin_shufflevector(v8, v8, 4, 5) + oh[2];
            oh[3] = a2 * __builtin_shufflevector(v8, v8, 6, 7) + oh[3];
        }
    }

    // ---- local exps with final m ----
#pragma unroll
    for (int l = 0; l < 9; ++l) { sl[l] = __expf(sl[l] - m); Z += sl[l]; }

    // ---- local AV: coef = el + lt*Z (unnormalized; final *invZ) ----
#pragma unroll
    for (int l = 0; l < 9; ++l) {
        const int di = l / 3 - 1, dj = l % 3 - 1;
        const int ii = i + di;
        const int jn = j + dj;
        const bool ok = (ii >= 0) && (ii < 64) && (jn >= 0) && (jn < 64);
        const int ic = max(min(ii, 63), 0);
        const int jc = max(min(jn, 63), 0);
        const float coef = ok ? (sl[l] + lt[l] * Z) : 0.f;
        const half8 v8 = *(const half8*)(kvh + ((size_t)(b * 4096 + ic * 64 + jc)) * 512 + 256 + h * 32 + co);
        const _Float16 ch = (_Float16)coef;
        const half2_t c2 = half2_t{ch, ch};
        oh[0] = c2 * __builtin_shufflevector(v8, v8, 0, 1) + oh[0];
        oh[1] = c2 * __builtin_shufflevector(v8, v8, 2, 3) + oh[1];
        oh[2] = c2 * __builtin_shufflevector(v8, v8, 4, 5) + oh[2];
        oh[3] = c2 * __builtin_shufflevector(v8, v8, 6, 7) + oh[3];
    }

    // ---- normalize and store fp16 ----
    const float invZ = 1.0f / Z;
    ushort4* outp = (ushort4*)(attno_hf + gq * 256 + h * 32 + co);
#pragma unroll
    for (int c4 = 0; c4 < 2; ++c4) {
        ushort4 u;
        u.x = f2h((float)oh[2*c4+0][0] * invZ);
        u.y = f2h((float)oh[2*c4+0][1] * invZ);
        u.z = f2h((float)oh[2*c4+1][0] * invZ);
        u.w = f2h((float)oh[2*c4+1][1] * invZ);
        outp[c4] = u;
    }
}

extern "C" void kernel_launch(void* const* d_in, const int* in_sizes, int n_in,
                              void* d_out, int out_size, void* d_ws, size_t ws_size,
                              hipStream_t stream)
{
    const float* x    = (const float*)d_in[0];
    const float* tbl  = (const float*)d_in[1];
    const float* sls  = (const float*)d_in[2];
    const float* q_w  = (const float*)d_in[3];
    const float* q_b  = (const float*)d_in[4];
    const float* kv_w = (const float*)d_in[5];
    const float* kv_b = (const float*)d_in[6];
    const float* temp = (const float*)d_in[7];
    const float* qe   = (const float*)d_in[8];
    const float* sr_w = (const float*)d_in[9];
    const float* sr_b = (const float*)d_in[10];
    const float* ng   = (const float*)d_in[11];
    const float* nb   = (const float*)d_in[12];
    const float* f1w  = (const float*)d_in[13];
    const float* f1b  = (const float*)d_in[14];
    const float* f2w  = (const float*)d_in[15];
    const float* f2b  = (const float*)d_in[16];
    const float* rbl  = (const float*)d_in[17];
    const float* ltok = (const float*)d_in[18];
    const float* lbias= (const float*)d_in[19];
    const float* pw   = (const float*)d_in[20];
    const float* pb   = (const float*)d_in[21];
    const int*   rpi  = (const int*)d_in[22];

    const int C = 256, Hh = 64, Ww = 64, Nn = Hh * Ww;
    const int B = in_sizes[0] / (Nn * C);   // 4
    const int T = in_sizes[1] / 2;
    const int M = B * Nn;                   // 16384

    float* ws = (float*)d_ws;
    size_t o = 0;
    ushort_t* qh   = (ushort_t*)(ws + o); o += (size_t)M * C / 2;  // fp16 q
    ushort_t* kvh  = (ushort_t*)(ws + o); o += (size_t)M * C;      // fp16 M x 512
    ushort_t* xsrh = (ushort_t*)(ws + o); o += (size_t)M * C / 2;  // fp16 xsr
    float* xpool = ws + o; o += (size_t)B * 64 * C;
    float* kvp   = ws + o; o += (size_t)B * 64 * 2 * C;
    float* cpbB  = ws + o; o += (size_t)T * 8;
    float* pbias = ws + o; o += (size_t)8 * Nn * 64;               // 8 MB (h,n,p)
    ushort_t* xh   = (ushort_t*)(ws + o); o += (size_t)M * C / 2;  // fp16 x; reused as attno
    ushort_t* Wall = (ushort_t*)(ws + o); o += 1024 * 256 / 2;
    ushort_t* Pwh  = (ushort_t*)(ws + o); o += 256 * 256 / 2;
    float* ball = ws + o; o += 1024;
    ushort_t* attno_hf = xh;   // xh dead after the x-GEMM

    dim3 blk(256);
    const int n4x = M * C / 4;

    // prep: cast x + pack weights (one kernel)
    prep<<<(n4x + 255) / 256, blk, 0, stream>>>(
        (const float4*)x, (ushort4*)xh, n4x,
        q_w, kv_w, sr_w, pw, q_b, kv_b, sr_b, Wall, Pwh, ball);
    // fused [q | k(norm) | v | sr(gelu)] fp16 GEMM
    mfma_hgemm<128><<<dim3(16, M / 128), blk, 0, stream>>>(
        xh, Wall, ball, nullptr, qh, kvh, xsrh, 0);
    // pool + LN -> kv_p (fp32 GEMM, tiny) -> normalize k_pool
    pool_ln<<<B * 64, blk, 0, stream>>>(xsrh, ng, nb, xpool, Hh, Ww);
    gemm_bias_act<<<dim3(2 * C / BN, (B * 64) / BM), blk, 0, stream>>>(xpool, kv_w, kv_b, kvp, B * 64, 2 * C, C, 0);
    headnorm<<<B * 64, blk, 0, stream>>>(kvp, 2 * C);
    // cpb + pool-bias expansion
    cpb_mlp_v2<<<(T + 3) / 4, blk, 0, stream>>>(tbl, f1w, f1b, f2w, f2b, cpbB, T);
    bias_expand_t<<<(8 * Nn * 64) / 256, blk, 0, stream>>>(rpi, cpbB, pbias);
    // attention (fp16 in/out)
    attn_v7<<<dim3(64, 8, B), blk, 0, stream>>>(
        qh, kvh, kvp, pbias, sls, temp, qe, rbl, ltok, lbias, attno_hf);
    // proj fp16 GEMM
    mfma_hgemm<64><<<dim3(4, M / 64), blk, 0, stream>>>(
        attno_hf, Pwh, pb, (float*)d_out, nullptr, nullptr, nullptr, 1);
}